// Round 1
// baseline (757.579 us; speedup 1.0000x reference)
//
#include <hip/hip_runtime.h>
#include <math.h>

constexpr int BN = 64;
constexpr int CC = 128;
constexpr int LL = 400;
constexpr int DK = 16;
constexpr int KK = 7;
constexpr int CL = CC * LL;              // 51200
constexpr int NBCL = BN * CL;            // 3276800
constexpr float EPSV = 1e-5f;
constexpr float INV_N = 1.0f / (float)CL;

// ---------------------------------------------------------------------------
// 1) out = x + pos_encoding, write res, accumulate LN stats (sum, sumsq) per b
// ---------------------------------------------------------------------------
__global__ __launch_bounds__(256) void addpos_stats_kernel(
    const float* __restrict__ x, float* __restrict__ res, float* __restrict__ stats)
{
  int idx = blockIdx.x * 256 + threadIdx.x;     // grid exactly covers NBCL
  int b  = idx / CL;
  int cl = idx - b * CL;
  int c  = cl / LL;
  int l  = cl - c * LL;
  float fc = (float)c;
  float freq, ph;
  if ((c & 1) == 0) { freq = powf(10000.f, -fc / (float)CC);        ph = 0.f; }
  else              { freq = -powf(10000.f, (1.f - fc) / (float)CC); ph = 1.5707963267948966f; }
  float v = x[idx] + sinf((float)l * freq + ph);
  res[idx] = v;
  // block covers a single b (CL % 256 == 0), reduce then 2 atomics
  float s1 = v, s2 = v * v;
  #pragma unroll
  for (int off = 32; off > 0; off >>= 1) {
    s1 += __shfl_down(s1, off);
    s2 += __shfl_down(s2, off);
  }
  __shared__ float r1[4], r2[4];
  int wv = threadIdx.x >> 6, lane = threadIdx.x & 63;
  if (lane == 0) { r1[wv] = s1; r2[wv] = s2; }
  __syncthreads();
  if (threadIdx.x == 0) {
    atomicAdd(&stats[b * 2 + 0], r1[0] + r1[1] + r1[2] + r1[3]);
    atomicAdd(&stats[b * 2 + 1], r2[0] + r2[1] + r2[2] + r2[3]);
  }
}

// ---------------------------------------------------------------------------
// 2) depthwise conv7 fused with on-the-fly LayerNorm of its input
//    xn = (res - mu) * rstd * g + beta ;  y = sum_j w[j]*xn[l+j-3] + db
// ---------------------------------------------------------------------------
__global__ __launch_bounds__(256) void dwln_kernel(
    const float* __restrict__ res, const float* __restrict__ stats,
    const float* __restrict__ lng, const float* __restrict__ lnb,
    const float* __restrict__ dww, const float* __restrict__ dwb,
    float* __restrict__ outp)
{
  __shared__ float sx[LL + 6];
  int bc = blockIdx.x;
  int b = bc >> 7, c = bc & 127;
  float s1 = stats[b * 2 + 0], s2 = stats[b * 2 + 1];
  float mu = s1 * INV_N;
  float rstd = rsqrtf(s2 * INV_N - mu * mu + EPSV);
  const float* rp = res + (size_t)b * CL + c * LL;
  const float* gp = lng + c * LL;
  const float* bp = lnb + c * LL;
  for (int i = threadIdx.x; i < LL + 6; i += 256) {
    int l = i - 3;
    float v = 0.f;
    if (l >= 0 && l < LL) v = (rp[l] - mu) * rstd * gp[l] + bp[l];
    sx[i] = v;
  }
  __syncthreads();
  float w[KK];
  #pragma unroll
  for (int j = 0; j < KK; j++) w[j] = dww[c * KK + j];   // wave-uniform
  float dbv = dwb[c];
  float* op = outp + (size_t)b * CL + c * LL;
  for (int l = threadIdx.x; l < LL; l += 256) {
    float a = dbv;
    #pragma unroll
    for (int j = 0; j < KK; j++) a += w[j] * sx[l + j];
    op[l] = a;
  }
}

// ---------------------------------------------------------------------------
// 3) universal GEMM: Y[b] = W(128x128) @ X[b](128x400) + bias, with optional
//    LN-on-load (LNX), ReLU, residual add, and LN-stats epilogue (STATS).
//    Block: 128 rows x 64 cols, 256 threads, thread tile 8x4.
// ---------------------------------------------------------------------------
template<bool LNX, bool RELU, bool ADDRES, bool STATS>
__global__ __launch_bounds__(256) void gemm_kernel(
    const float* __restrict__ W, const float* __restrict__ X,
    const float* __restrict__ bias, const float* __restrict__ resid,
    const float* __restrict__ lng, const float* __restrict__ lnb,
    const float* __restrict__ statsIn, float* __restrict__ statsOut,
    float* __restrict__ Y)
{
  __shared__ float Xs[CC][68];    // 68: keep rows 16B-aligned, break conflicts
  __shared__ float Ws[32][132];
  __shared__ float red[8];
  int tid = threadIdx.x;
  int bb = blockIdx.y;
  int j0 = blockIdx.x * 64;
  float mu = 0.f, rstd = 0.f;
  if (LNX) {
    float s1 = statsIn[bb * 2 + 0], s2 = statsIn[bb * 2 + 1];
    mu = s1 * INV_N;
    rstd = rsqrtf(s2 * INV_N - mu * mu + EPSV);
  }
  const float* Xb = X + (size_t)bb * CL;
  for (int idx = tid; idx < CC * 64; idx += 256) {
    int r = idx >> 6, c2 = idx & 63;
    int col = j0 + c2;
    float v = 0.f;
    if (col < LL) {
      v = Xb[r * LL + col];
      if (LNX) v = (v - mu) * rstd * lng[r * LL + col] + lnb[r * LL + col];
    }
    Xs[r][c2] = v;
  }
  int cg = tid & 15, rg = tid >> 4;        // 16 col-groups x 16 row-groups
  float4 acc[8];
  #pragma unroll
  for (int r = 0; r < 8; r++) acc[r] = make_float4(0.f, 0.f, 0.f, 0.f);
  for (int kt = 0; kt < 4; ++kt) {
    __syncthreads();
    for (int idx = tid; idx < CC * 32; idx += 256) {
      int o = idx >> 5, c2 = idx & 31;
      Ws[c2][o] = W[o * CC + kt * 32 + c2];
    }
    __syncthreads();
    #pragma unroll 4
    for (int c2 = 0; c2 < 32; ++c2) {
      const float4 xv = *reinterpret_cast<const float4*>(&Xs[kt * 32 + c2][cg * 4]);
      const float4 w0 = *reinterpret_cast<const float4*>(&Ws[c2][rg * 8]);
      const float4 w1 = *reinterpret_cast<const float4*>(&Ws[c2][rg * 8 + 4]);
      float wvv[8] = {w0.x, w0.y, w0.z, w0.w, w1.x, w1.y, w1.z, w1.w};
      #pragma unroll
      for (int r = 0; r < 8; r++) {
        acc[r].x += wvv[r] * xv.x;
        acc[r].y += wvv[r] * xv.y;
        acc[r].z += wvv[r] * xv.z;
        acc[r].w += wvv[r] * xv.w;
      }
    }
  }
  float lsum = 0.f, lsq = 0.f;
  int colb = j0 + cg * 4;
  if (colb < LL) {                          // L % 4 == 0 so float4 all-or-none
    #pragma unroll
    for (int r = 0; r < 8; r++) {
      int o = rg * 8 + r;
      float bv = bias[o];
      float4 v = acc[r];
      v.x += bv; v.y += bv; v.z += bv; v.w += bv;
      if (RELU) {
        v.x = fmaxf(v.x, 0.f); v.y = fmaxf(v.y, 0.f);
        v.z = fmaxf(v.z, 0.f); v.w = fmaxf(v.w, 0.f);
      }
      size_t oidx = (size_t)bb * CL + (size_t)o * LL + colb;
      if (ADDRES) {
        const float4 rr = *reinterpret_cast<const float4*>(&resid[oidx]);
        v.x += rr.x; v.y += rr.y; v.z += rr.z; v.w += rr.w;
      }
      *reinterpret_cast<float4*>(&Y[oidx]) = v;
      if (STATS) {
        lsum += v.x + v.y + v.z + v.w;
        lsq  += v.x * v.x + v.y * v.y + v.z * v.z + v.w * v.w;
      }
    }
  }
  if (STATS) {
    #pragma unroll
    for (int off = 32; off > 0; off >>= 1) {
      lsum += __shfl_down(lsum, off);
      lsq  += __shfl_down(lsq, off);
    }
    int wv = tid >> 6, lane = tid & 63;
    if (lane == 0) { red[wv * 2] = lsum; red[wv * 2 + 1] = lsq; }
    __syncthreads();
    if (tid == 0) {
      atomicAdd(&statsOut[bb * 2 + 0], red[0] + red[2] + red[4] + red[6]);
      atomicAdd(&statsOut[bb * 2 + 1], red[1] + red[3] + red[5] + red[7]);
    }
  }
}

// ---------------------------------------------------------------------------
// 4) attention: lane = query row, K/V read via wave-uniform (scalar) loads,
//    online softmax in registers. Layout (B,C,L), c = h*16+d.
// ---------------------------------------------------------------------------
__global__ __launch_bounds__(256) void attn_kernel(
    const float* __restrict__ qb, const float* __restrict__ kb,
    const float* __restrict__ vb, const float* __restrict__ mask,
    float* __restrict__ ao)
{
  int bh = blockIdx.x;
  int b = bh >> 3, h = bh & 7;
  int wv = threadIdx.x >> 6, lane = threadIdx.x & 63;
  int tile = blockIdx.y * 4 + wv;
  if (tile >= 7) return;                    // wave-uniform exit
  int l = tile * 64 + lane;
  bool active = l < LL;
  int lc = active ? l : (LL - 1);
  size_t base = ((size_t)b * CC + h * DK) * LL;
  const float* qp = qb + base;
  const float* kp = kb + base;
  const float* vp = vb + base;
  const float* mp = mask + (size_t)b * LL;
  float q[DK];
  #pragma unroll
  for (int d = 0; d < DK; d++) q[d] = qp[d * LL + lc];
  float acc[DK];
  #pragma unroll
  for (int d = 0; d < DK; d++) acc[d] = 0.f;
  float mx = -INFINITY, sum = 0.f;
  const float scale = 0.08838834764831845f;   // 1/sqrt(128)
  for (int m0 = 0; m0 < LL; m0 += 16) {
    float s[16];
    #pragma unroll
    for (int mm = 0; mm < 16; mm++) s[mm] = 0.f;
    #pragma unroll
    for (int d = 0; d < DK; d++) {
      const float qd = q[d];
      const float* krow = kp + d * LL + m0;   // uniform address -> s_load
      #pragma unroll
      for (int mm = 0; mm < 16; mm++) s[mm] += qd * krow[mm];
    }
    float mxc = mx;
    #pragma unroll
    for (int mm = 0; mm < 16; mm++) {
      float mv = mp[m0 + mm];
      float sv = s[mm] * scale;
      sv = sv * mv + (1.f - mv) * (-1e30f);
      s[mm] = sv;
      mxc = fmaxf(mxc, sv);
    }
    float alpha = expf(mx - mxc);
    sum *= alpha;
    #pragma unroll
    for (int mm = 0; mm < 16; mm++) {
      float p = expf(s[mm] - mxc);
      s[mm] = p;
      sum += p;
    }
    #pragma unroll
    for (int d = 0; d < DK; d++) {
      const float* vrow = vp + d * LL + m0;
      float a = acc[d] * alpha;
      #pragma unroll
      for (int mm = 0; mm < 16; mm++) a += s[mm] * vrow[mm];
      acc[d] = a;
    }
    mx = mxc;
  }
  if (active) {
    float inv = 1.f / sum;
    float* aop = ao + base;
    #pragma unroll
    for (int d = 0; d < DK; d++) aop[d * LL + l] = acc[d] * inv;
  }
}

// ---------------------------------------------------------------------------
extern "C" void kernel_launch(void* const* d_in, const int* in_sizes, int n_in,
                              void* d_out, int out_size, void* d_ws, size_t ws_size,
                              hipStream_t stream) {
  const float* x    = (const float*)d_in[0];
  const float* mask = (const float*)d_in[1];
  const float* dw_w = (const float*)d_in[2];
  const float* dw_b = (const float*)d_in[3];
  const float* pw_w = (const float*)d_in[4];
  const float* pw_b = (const float*)d_in[5];
  const float* wq   = (const float*)d_in[6];
  const float* bq   = (const float*)d_in[7];
  const float* wk   = (const float*)d_in[8];
  const float* bk   = (const float*)d_in[9];
  const float* wvp  = (const float*)d_in[10];
  const float* bv   = (const float*)d_in[11];
  const float* wo   = (const float*)d_in[12];
  const float* bo   = (const float*)d_in[13];
  const float* fcw  = (const float*)d_in[14];
  const float* fcb  = (const float*)d_in[15];
  const float* lng  = (const float*)d_in[16];
  const float* lnb  = (const float*)d_in[17];
  float* out = (float*)d_out;
  float* ws  = (float*)d_ws;

  float* stats = ws;                // 6 regions * 128 floats (64 b * {sum,sumsq})
  float* res = ws + 1024;
  float* tmp = res + NBCL;
  float* qb  = tmp + NBCL;
  float* kb  = qb + NBCL;
  float* vb  = kb + NBCL;

  hipMemsetAsync(stats, 0, 768 * sizeof(float), stream);
  addpos_stats_kernel<<<NBCL / 256, 256, 0, stream>>>(x, res, stats);

  for (int i = 0; i < 4; i++) {
    dwln_kernel<<<BN * CC, 256, 0, stream>>>(
        res, stats + i * 128, lng, lnb, dw_w + i * CC * KK, dw_b + i * CC, tmp);
    gemm_kernel<false, true, true, true><<<dim3(7, BN), 256, 0, stream>>>(
        pw_w + i * CC * CC, tmp, pw_b + i * CC, res,
        nullptr, nullptr, nullptr, stats + (i + 1) * 128, res);
  }
  // QKV (LN fused into X load, stats[4])
  gemm_kernel<true, false, false, false><<<dim3(7, BN), 256, 0, stream>>>(
      wq, res, bq, nullptr, lng, lnb, stats + 4 * 128, nullptr, qb);
  gemm_kernel<true, false, false, false><<<dim3(7, BN), 256, 0, stream>>>(
      wk, res, bk, nullptr, lng, lnb, stats + 4 * 128, nullptr, kb);
  gemm_kernel<true, false, false, false><<<dim3(7, BN), 256, 0, stream>>>(
      wvp, res, bv, nullptr, lng, lnb, stats + 4 * 128, nullptr, vb);
  // attention -> tmp
  attn_kernel<<<dim3(512, 2), 256, 0, stream>>>(qb, kb, vb, mask, tmp);
  // WO projection + residual -> res, stats[5]
  gemm_kernel<false, false, true, true><<<dim3(7, BN), 256, 0, stream>>>(
      wo, tmp, bo, res, nullptr, nullptr, nullptr, stats + 5 * 128, res);
  // FC (LN on load) + ReLU + residual -> d_out
  gemm_kernel<true, true, true, false><<<dim3(7, BN), 256, 0, stream>>>(
      fcw, res, fcb, res, lng, lnb, stats + 5 * 128, nullptr, out);
}

// Round 2
// 647.832 us; speedup vs baseline: 1.1694x; 1.1694x over previous
//
#include <hip/hip_runtime.h>
#include <math.h>

constexpr int BN = 64;
constexpr int CC = 128;
constexpr int LL = 400;
constexpr int DK = 16;
constexpr int KK = 7;
constexpr int CL = CC * LL;              // 51200
constexpr int NBCL = BN * CL;            // 3276800
constexpr float EPSV = 1e-5f;
constexpr float INV_N = 1.0f / (float)CL;

// ---------------------------------------------------------------------------
// 1) out = x + pos_encoding, write res, accumulate LN stats (sum, sumsq) per b
// ---------------------------------------------------------------------------
__global__ __launch_bounds__(256) void addpos_stats_kernel(
    const float* __restrict__ x, float* __restrict__ res, float* __restrict__ stats)
{
  int idx = blockIdx.x * 256 + threadIdx.x;     // grid exactly covers NBCL
  int b  = idx / CL;
  int cl = idx - b * CL;
  int c  = cl / LL;
  int l  = cl - c * LL;
  float fc = (float)c;
  float freq, ph;
  if ((c & 1) == 0) { freq = powf(10000.f, -fc / (float)CC);        ph = 0.f; }
  else              { freq = -powf(10000.f, (1.f - fc) / (float)CC); ph = 1.5707963267948966f; }
  float v = x[idx] + sinf((float)l * freq + ph);
  res[idx] = v;
  float s1 = v, s2 = v * v;
  #pragma unroll
  for (int off = 32; off > 0; off >>= 1) {
    s1 += __shfl_down(s1, off);
    s2 += __shfl_down(s2, off);
  }
  __shared__ float r1[4], r2[4];
  int wv = threadIdx.x >> 6, lane = threadIdx.x & 63;
  if (lane == 0) { r1[wv] = s1; r2[wv] = s2; }
  __syncthreads();
  if (threadIdx.x == 0) {
    atomicAdd(&stats[b * 2 + 0], r1[0] + r1[1] + r1[2] + r1[3]);
    atomicAdd(&stats[b * 2 + 1], r2[0] + r2[1] + r2[2] + r2[3]);
  }
}

// ---------------------------------------------------------------------------
// 2) depthwise conv7 fused with on-the-fly LayerNorm of its input
// ---------------------------------------------------------------------------
__global__ __launch_bounds__(256) void dwln_kernel(
    const float* __restrict__ res, const float* __restrict__ stats,
    const float* __restrict__ lng, const float* __restrict__ lnb,
    const float* __restrict__ dww, const float* __restrict__ dwb,
    float* __restrict__ outp)
{
  __shared__ float sx[LL + 6];
  int bc = blockIdx.x;
  int b = bc >> 7, c = bc & 127;
  float s1 = stats[b * 2 + 0], s2 = stats[b * 2 + 1];
  float mu = s1 * INV_N;
  float rstd = rsqrtf(s2 * INV_N - mu * mu + EPSV);
  const float* rp = res + (size_t)b * CL + c * LL;
  const float* gp = lng + c * LL;
  const float* bp = lnb + c * LL;
  for (int i = threadIdx.x; i < LL + 6; i += 256) {
    int l = i - 3;
    float v = 0.f;
    if (l >= 0 && l < LL) v = (rp[l] - mu) * rstd * gp[l] + bp[l];
    sx[i] = v;
  }
  __syncthreads();
  float w[KK];
  #pragma unroll
  for (int j = 0; j < KK; j++) w[j] = dww[c * KK + j];   // wave-uniform
  float dbv = dwb[c];
  float* op = outp + (size_t)b * CL + c * LL;
  for (int l = threadIdx.x; l < LL; l += 256) {
    float a = dbv;
    #pragma unroll
    for (int j = 0; j < KK; j++) a += w[j] * sx[l + j];
    op[l] = a;
  }
}

// ---------------------------------------------------------------------------
// 3) universal GEMM body: Y[b] = W(128x128) @ X[b](128x400) + bias.
//    512 threads, block tile 128 rows x 64 cols, thread tile 4x4.
// ---------------------------------------------------------------------------
template<bool LNX, bool RELU, bool ADDRES, bool STATS>
__device__ __forceinline__ void gemm_body(
    const float* __restrict__ W, const float* __restrict__ X,
    const float* __restrict__ bias, const float* __restrict__ resid,
    const float* __restrict__ lng, const float* __restrict__ lnb,
    const float* __restrict__ statsIn, float* __restrict__ statsOut,
    float* __restrict__ Y)
{
  __shared__ float Xs[CC][68];    // 272B row stride: 16B aligned
  __shared__ float Ws[32][132];
  __shared__ float red[16];
  int tid = threadIdx.x;
  int bb = blockIdx.y;
  int j0 = blockIdx.x * 64;
  float mu = 0.f, rstd = 0.f;
  if (LNX) {
    float s1 = statsIn[bb * 2 + 0], s2 = statsIn[bb * 2 + 1];
    mu = s1 * INV_N;
    rstd = rsqrtf(s2 * INV_N - mu * mu + EPSV);
  }
  const float* Xb = X + (size_t)bb * CL;
  for (int idx = tid; idx < CC * 64; idx += 512) {
    int r = idx >> 6, c2 = idx & 63;
    int col = j0 + c2;
    float v = 0.f;
    if (col < LL) {
      v = Xb[r * LL + col];
      if (LNX) v = (v - mu) * rstd * lng[r * LL + col] + lnb[r * LL + col];
    }
    Xs[r][c2] = v;
  }
  int cg = tid & 15, rg = tid >> 4;        // 16 col-groups x 32 row-groups
  float4 acc[4];
  #pragma unroll
  for (int r = 0; r < 4; r++) acc[r] = make_float4(0.f, 0.f, 0.f, 0.f);
  for (int kt = 0; kt < 4; ++kt) {
    __syncthreads();
    for (int idx = tid; idx < CC * 32; idx += 512) {
      int o = idx >> 5, c2 = idx & 31;
      Ws[c2][o] = W[o * CC + kt * 32 + c2];
    }
    __syncthreads();
    #pragma unroll 8
    for (int c2 = 0; c2 < 32; ++c2) {
      const float4 xv = *reinterpret_cast<const float4*>(&Xs[kt * 32 + c2][cg * 4]);
      const float4 wv = *reinterpret_cast<const float4*>(&Ws[c2][rg * 4]);
      float wvv[4] = {wv.x, wv.y, wv.z, wv.w};
      #pragma unroll
      for (int r = 0; r < 4; r++) {
        acc[r].x += wvv[r] * xv.x;
        acc[r].y += wvv[r] * xv.y;
        acc[r].z += wvv[r] * xv.z;
        acc[r].w += wvv[r] * xv.w;
      }
    }
  }
  float lsum = 0.f, lsq = 0.f;
  int colb = j0 + cg * 4;
  if (colb < LL) {                          // L % 4 == 0 so float4 all-or-none
    #pragma unroll
    for (int r = 0; r < 4; r++) {
      int o = rg * 4 + r;
      float bv = bias[o];
      float4 v = acc[r];
      v.x += bv; v.y += bv; v.z += bv; v.w += bv;
      if (RELU) {
        v.x = fmaxf(v.x, 0.f); v.y = fmaxf(v.y, 0.f);
        v.z = fmaxf(v.z, 0.f); v.w = fmaxf(v.w, 0.f);
      }
      size_t oidx = (size_t)bb * CL + (size_t)o * LL + colb;
      if (ADDRES) {
        const float4 rr = *reinterpret_cast<const float4*>(&resid[oidx]);
        v.x += rr.x; v.y += rr.y; v.z += rr.z; v.w += rr.w;
      }
      *reinterpret_cast<float4*>(&Y[oidx]) = v;
      if (STATS) {
        lsum += v.x + v.y + v.z + v.w;
        lsq  += v.x * v.x + v.y * v.y + v.z * v.z + v.w * v.w;
      }
    }
  }
  if (STATS) {
    #pragma unroll
    for (int off = 32; off > 0; off >>= 1) {
      lsum += __shfl_down(lsum, off);
      lsq  += __shfl_down(lsq, off);
    }
    int wv2 = tid >> 6, lane = tid & 63;
    if (lane == 0) { red[wv2 * 2] = lsum; red[wv2 * 2 + 1] = lsq; }
    __syncthreads();
    if (tid == 0) {
      float a = 0.f, b2 = 0.f;
      #pragma unroll
      for (int w2 = 0; w2 < 8; w2++) { a += red[w2 * 2]; b2 += red[w2 * 2 + 1]; }
      atomicAdd(&statsOut[bb * 2 + 0], a);
      atomicAdd(&statsOut[bb * 2 + 1], b2);
    }
  }
}

template<bool LNX, bool RELU, bool ADDRES, bool STATS>
__global__ __launch_bounds__(512, 1) void gemm_kernel(
    const float* __restrict__ W, const float* __restrict__ X,
    const float* __restrict__ bias, const float* __restrict__ resid,
    const float* __restrict__ lng, const float* __restrict__ lnb,
    const float* __restrict__ statsIn, float* __restrict__ statsOut,
    float* __restrict__ Y)
{
  gemm_body<LNX, RELU, ADDRES, STATS>(W, X, bias, resid, lng, lnb, statsIn, statsOut, Y);
}

// QKV: three GEMMs sharing X, selected by blockIdx.z
__global__ __launch_bounds__(512, 1) void qkv_kernel(
    const float* __restrict__ wq, const float* __restrict__ wk, const float* __restrict__ wv,
    const float* __restrict__ bq, const float* __restrict__ bk, const float* __restrict__ bv,
    const float* __restrict__ X,
    const float* __restrict__ lng, const float* __restrict__ lnb,
    const float* __restrict__ statsIn,
    float* __restrict__ qb, float* __restrict__ kb, float* __restrict__ vb)
{
  const float* W = wq; const float* bias = bq; float* Y = qb;
  if (blockIdx.z == 1) { W = wk; bias = bk; Y = kb; }
  else if (blockIdx.z == 2) { W = wv; bias = bv; Y = vb; }
  gemm_body<true, false, false, false>(W, X, bias, nullptr, lng, lnb, statsIn, nullptr, Y);
}

// ---------------------------------------------------------------------------
// 4) attention: one wave per (b,h,64-query tile); K/V via wave-uniform scalar
//    loads; online softmax in exp2 domain (log2e folded into scale).
// ---------------------------------------------------------------------------
__global__ __launch_bounds__(64, 4) void attn_kernel(
    const float* __restrict__ qb, const float* __restrict__ kb,
    const float* __restrict__ vb, const float* __restrict__ mask,
    float* __restrict__ ao)
{
  int bh = blockIdx.x;
  int b = bh >> 3, h = bh & 7;
  int lane = threadIdx.x;
  int l = blockIdx.y * 64 + lane;
  bool active = l < LL;
  int lc = active ? l : (LL - 1);
  size_t base = ((size_t)b * CC + h * DK) * LL;
  const float* qp = qb + base;
  const float* kp = kb + base;
  const float* vp = vb + base;
  const float* mp = mask + (size_t)b * LL;
  float q[DK];
  #pragma unroll
  for (int d = 0; d < DK; d++) q[d] = qp[d * LL + lc];
  float acc[DK];
  #pragma unroll
  for (int d = 0; d < DK; d++) acc[d] = 0.f;
  float mx = -3.0e38f, sum = 0.f;
  // 1/sqrt(128) * log2(e): softmax computed in exp2 domain (exact transform)
  const float scale2 = 0.08838834764831845f * 1.4426950408889634f;
  for (int m0 = 0; m0 < LL; m0 += 16) {
    float s[16];
    #pragma unroll
    for (int mm = 0; mm < 16; mm++) s[mm] = 0.f;
    #pragma unroll
    for (int d = 0; d < DK; d++) {
      const float qd = q[d];
      const float* krow = kp + d * LL + m0;   // uniform address -> s_load
      #pragma unroll
      for (int mm = 0; mm < 16; mm++) s[mm] += qd * krow[mm];
    }
    float mxc = mx;
    #pragma unroll
    for (int mm = 0; mm < 16; mm++) {
      float mv = mp[m0 + mm];
      float sv = (s[mm] * scale2) * mv + (1.f - mv) * (-1.4427e30f);
      s[mm] = sv;
      mxc = fmaxf(mxc, sv);
    }
    float alpha = exp2f(mx - mxc);
    sum *= alpha;
    #pragma unroll
    for (int mm = 0; mm < 16; mm++) {
      float p = exp2f(s[mm] - mxc);
      s[mm] = p;
      sum += p;
    }
    #pragma unroll
    for (int d = 0; d < DK; d++) {
      const float* vrow = vp + d * LL + m0;
      float a = acc[d] * alpha;
      #pragma unroll
      for (int mm = 0; mm < 16; mm++) a += s[mm] * vrow[mm];
      acc[d] = a;
    }
    mx = mxc;
  }
  if (active) {
    float inv = 1.f / sum;
    float* aop = ao + base;
    #pragma unroll
    for (int d = 0; d < DK; d++) aop[d * LL + l] = acc[d] * inv;
  }
}

// ---------------------------------------------------------------------------
extern "C" void kernel_launch(void* const* d_in, const int* in_sizes, int n_in,
                              void* d_out, int out_size, void* d_ws, size_t ws_size,
                              hipStream_t stream) {
  const float* x    = (const float*)d_in[0];
  const float* mask = (const float*)d_in[1];
  const float* dw_w = (const float*)d_in[2];
  const float* dw_b = (const float*)d_in[3];
  const float* pw_w = (const float*)d_in[4];
  const float* pw_b = (const float*)d_in[5];
  const float* wq   = (const float*)d_in[6];
  const float* bq   = (const float*)d_in[7];
  const float* wk   = (const float*)d_in[8];
  const float* bk   = (const float*)d_in[9];
  const float* wvp  = (const float*)d_in[10];
  const float* bv   = (const float*)d_in[11];
  const float* wo   = (const float*)d_in[12];
  const float* bo   = (const float*)d_in[13];
  const float* fcw  = (const float*)d_in[14];
  const float* fcb  = (const float*)d_in[15];
  const float* lng  = (const float*)d_in[16];
  const float* lnb  = (const float*)d_in[17];
  float* out = (float*)d_out;
  float* ws  = (float*)d_ws;

  float* stats = ws;                // 6 regions * 128 floats (64 b * {sum,sumsq})
  float* res = ws + 1024;
  float* tmp = res + NBCL;
  float* qb  = tmp + NBCL;
  float* kb  = qb + NBCL;
  float* vb  = kb + NBCL;

  hipMemsetAsync(stats, 0, 768 * sizeof(float), stream);
  addpos_stats_kernel<<<NBCL / 256, 256, 0, stream>>>(x, res, stats);

  for (int i = 0; i < 4; i++) {
    dwln_kernel<<<BN * CC, 256, 0, stream>>>(
        res, stats + i * 128, lng, lnb, dw_w + i * CC * KK, dw_b + i * CC, tmp);
    gemm_kernel<false, true, true, true><<<dim3(7, BN), 512, 0, stream>>>(
        pw_w + i * CC * CC, tmp, pw_b + i * CC, res,
        nullptr, nullptr, nullptr, stats + (i + 1) * 128, res);
  }
  // QKV in one dispatch (LN fused into X load, stats[4])
  qkv_kernel<<<dim3(7, BN, 3), 512, 0, stream>>>(
      wq, wk, wvp, bq, bk, bv, res, lng, lnb, stats + 4 * 128, qb, kb, vb);
  // attention -> tmp
  attn_kernel<<<dim3(512, 7), 64, 0, stream>>>(qb, kb, vb, mask, tmp);
  // WO projection + residual -> res, stats[5]
  gemm_kernel<false, false, true, true><<<dim3(7, BN), 512, 0, stream>>>(
      wo, tmp, bo, res, nullptr, nullptr, nullptr, stats + 5 * 128, res);
  // FC (LN on load) + ReLU + residual -> d_out
  gemm_kernel<true, true, true, false><<<dim3(7, BN), 512, 0, stream>>>(
      fcw, res, fcb, res, lng, lnb, stats + 5 * 128, nullptr, out);
}

// Round 3
// 535.586 us; speedup vs baseline: 1.4145x; 1.2096x over previous
//
#include <hip/hip_runtime.h>
#include <math.h>

constexpr int BN = 64;
constexpr int CC = 128;
constexpr int LL = 400;
constexpr int DK = 16;
constexpr int KK = 7;
constexpr int CL = CC * LL;              // 51200
constexpr int NBCL = BN * CL;            // 3276800
constexpr float EPSV = 1e-5f;
constexpr float INV_N = 1.0f / (float)CL;

typedef __attribute__((ext_vector_type(8))) short bf16x8;
typedef __attribute__((ext_vector_type(4))) float f32x4;

__device__ __forceinline__ short f2bf(float f) {
  unsigned u = __builtin_bit_cast(unsigned, f);
  u = (u + 0x7fffu + ((u >> 16) & 1u)) >> 16;
  return (short)u;
}

// ---------------------------------------------------------------------------
// 1) out = x + pos_encoding, write res, accumulate LN stats (sum, sumsq) per b
// ---------------------------------------------------------------------------
__global__ __launch_bounds__(256) void addpos_stats_kernel(
    const float* __restrict__ x, float* __restrict__ res, float* __restrict__ stats)
{
  int idx = blockIdx.x * 256 + threadIdx.x;     // grid exactly covers NBCL
  int b  = idx / CL;
  int cl = idx - b * CL;
  int c  = cl / LL;
  int l  = cl - c * LL;
  float fc = (float)c;
  float freq, ph;
  if ((c & 1) == 0) { freq = powf(10000.f, -fc / (float)CC);        ph = 0.f; }
  else              { freq = -powf(10000.f, (1.f - fc) / (float)CC); ph = 1.5707963267948966f; }
  float v = x[idx] + sinf((float)l * freq + ph);
  res[idx] = v;
  float s1 = v, s2 = v * v;
  #pragma unroll
  for (int off = 32; off > 0; off >>= 1) {
    s1 += __shfl_down(s1, off);
    s2 += __shfl_down(s2, off);
  }
  __shared__ float r1[4], r2[4];
  int wv = threadIdx.x >> 6, lane = threadIdx.x & 63;
  if (lane == 0) { r1[wv] = s1; r2[wv] = s2; }
  __syncthreads();
  if (threadIdx.x == 0) {
    atomicAdd(&stats[b * 2 + 0], r1[0] + r1[1] + r1[2] + r1[3]);
    atomicAdd(&stats[b * 2 + 1], r2[0] + r2[1] + r2[2] + r2[3]);
  }
}

// ---------------------------------------------------------------------------
// 2) depthwise conv7 fused with on-the-fly LayerNorm of its input
// ---------------------------------------------------------------------------
__global__ __launch_bounds__(256) void dwln_kernel(
    const float* __restrict__ res, const float* __restrict__ stats,
    const float* __restrict__ lng, const float* __restrict__ lnb,
    const float* __restrict__ dww, const float* __restrict__ dwb,
    float* __restrict__ outp)
{
  __shared__ float sx[LL + 6];
  int bc = blockIdx.x;
  int b = bc >> 7, c = bc & 127;
  float s1 = stats[b * 2 + 0], s2 = stats[b * 2 + 1];
  float mu = s1 * INV_N;
  float rstd = rsqrtf(s2 * INV_N - mu * mu + EPSV);
  const float* rp = res + (size_t)b * CL + c * LL;
  const float* gp = lng + c * LL;
  const float* bp = lnb + c * LL;
  for (int i = threadIdx.x; i < LL + 6; i += 256) {
    int l = i - 3;
    float v = 0.f;
    if (l >= 0 && l < LL) v = (rp[l] - mu) * rstd * gp[l] + bp[l];
    sx[i] = v;
  }
  __syncthreads();
  float w[KK];
  #pragma unroll
  for (int j = 0; j < KK; j++) w[j] = dww[c * KK + j];   // wave-uniform
  float dbv = dwb[c];
  float* op = outp + (size_t)b * CL + c * LL;
  for (int l = threadIdx.x; l < LL; l += 256) {
    float a = dbv;
    #pragma unroll
    for (int j = 0; j < KK; j++) a += w[j] * sx[l + j];
    op[l] = a;
  }
}

// ---------------------------------------------------------------------------
// 3) universal GEMM body: Y[b] = W(128x128) @ X[b](128x400) + bias.
//    512 threads, block tile 128 rows x 64 cols, thread tile 4x4.
// ---------------------------------------------------------------------------
template<bool LNX, bool RELU, bool ADDRES, bool STATS>
__device__ __forceinline__ void gemm_body(
    const float* __restrict__ W, const float* __restrict__ X,
    const float* __restrict__ bias, const float* __restrict__ resid,
    const float* __restrict__ lng, const float* __restrict__ lnb,
    const float* __restrict__ statsIn, float* __restrict__ statsOut,
    float* __restrict__ Y)
{
  __shared__ float Xs[CC][68];    // 272B row stride: 16B aligned
  __shared__ float Ws[32][132];
  __shared__ float red[16];
  int tid = threadIdx.x;
  int bb = blockIdx.y;
  int j0 = blockIdx.x * 64;
  float mu = 0.f, rstd = 0.f;
  if (LNX) {
    float s1 = statsIn[bb * 2 + 0], s2 = statsIn[bb * 2 + 1];
    mu = s1 * INV_N;
    rstd = rsqrtf(s2 * INV_N - mu * mu + EPSV);
  }
  const float* Xb = X + (size_t)bb * CL;
  for (int idx = tid; idx < CC * 64; idx += 512) {
    int r = idx >> 6, c2 = idx & 63;
    int col = j0 + c2;
    float v = 0.f;
    if (col < LL) {
      v = Xb[r * LL + col];
      if (LNX) v = (v - mu) * rstd * lng[r * LL + col] + lnb[r * LL + col];
    }
    Xs[r][c2] = v;
  }
  int cg = tid & 15, rg = tid >> 4;        // 16 col-groups x 32 row-groups
  float4 acc[4];
  #pragma unroll
  for (int r = 0; r < 4; r++) acc[r] = make_float4(0.f, 0.f, 0.f, 0.f);
  for (int kt = 0; kt < 4; ++kt) {
    __syncthreads();
    for (int idx = tid; idx < CC * 32; idx += 512) {
      int o = idx >> 5, c2 = idx & 31;
      Ws[c2][o] = W[o * CC + kt * 32 + c2];
    }
    __syncthreads();
    #pragma unroll 8
    for (int c2 = 0; c2 < 32; ++c2) {
      const float4 xv = *reinterpret_cast<const float4*>(&Xs[kt * 32 + c2][cg * 4]);
      const float4 wv = *reinterpret_cast<const float4*>(&Ws[c2][rg * 4]);
      float wvv[4] = {wv.x, wv.y, wv.z, wv.w};
      #pragma unroll
      for (int r = 0; r < 4; r++) {
        acc[r].x += wvv[r] * xv.x;
        acc[r].y += wvv[r] * xv.y;
        acc[r].z += wvv[r] * xv.z;
        acc[r].w += wvv[r] * xv.w;
      }
    }
  }
  float lsum = 0.f, lsq = 0.f;
  int colb = j0 + cg * 4;
  if (colb < LL) {                          // L % 4 == 0 so float4 all-or-none
    #pragma unroll
    for (int r = 0; r < 4; r++) {
      int o = rg * 4 + r;
      float bv = bias[o];
      float4 v = acc[r];
      v.x += bv; v.y += bv; v.z += bv; v.w += bv;
      if (RELU) {
        v.x = fmaxf(v.x, 0.f); v.y = fmaxf(v.y, 0.f);
        v.z = fmaxf(v.z, 0.f); v.w = fmaxf(v.w, 0.f);
      }
      size_t oidx = (size_t)bb * CL + (size_t)o * LL + colb;
      if (ADDRES) {
        const float4 rr = *reinterpret_cast<const float4*>(&resid[oidx]);
        v.x += rr.x; v.y += rr.y; v.z += rr.z; v.w += rr.w;
      }
      *reinterpret_cast<float4*>(&Y[oidx]) = v;
      if (STATS) {
        lsum += v.x + v.y + v.z + v.w;
        lsq  += v.x * v.x + v.y * v.y + v.z * v.z + v.w * v.w;
      }
    }
  }
  if (STATS) {
    #pragma unroll
    for (int off = 32; off > 0; off >>= 1) {
      lsum += __shfl_down(lsum, off);
      lsq  += __shfl_down(lsq, off);
    }
    int wv2 = tid >> 6, lane = tid & 63;
    if (lane == 0) { red[wv2 * 2] = lsum; red[wv2 * 2 + 1] = lsq; }
    __syncthreads();
    if (tid == 0) {
      float a = 0.f, b2 = 0.f;
      #pragma unroll
      for (int w2 = 0; w2 < 8; w2++) { a += red[w2 * 2]; b2 += red[w2 * 2 + 1]; }
      atomicAdd(&statsOut[bb * 2 + 0], a);
      atomicAdd(&statsOut[bb * 2 + 1], b2);
    }
  }
}

template<bool LNX, bool RELU, bool ADDRES, bool STATS>
__global__ __launch_bounds__(512, 1) void gemm_kernel(
    const float* __restrict__ W, const float* __restrict__ X,
    const float* __restrict__ bias, const float* __restrict__ resid,
    const float* __restrict__ lng, const float* __restrict__ lnb,
    const float* __restrict__ statsIn, float* __restrict__ statsOut,
    float* __restrict__ Y)
{
  gemm_body<LNX, RELU, ADDRES, STATS>(W, X, bias, resid, lng, lnb, statsIn, statsOut, Y);
}

// QKV: three GEMMs sharing X, selected by blockIdx.z
__global__ __launch_bounds__(512, 1) void qkv_kernel(
    const float* __restrict__ wq, const float* __restrict__ wk, const float* __restrict__ wv,
    const float* __restrict__ bq, const float* __restrict__ bk, const float* __restrict__ bv,
    const float* __restrict__ X,
    const float* __restrict__ lng, const float* __restrict__ lnb,
    const float* __restrict__ statsIn,
    float* __restrict__ qb, float* __restrict__ kb, float* __restrict__ vb)
{
  const float* W = wq; const float* bias = bq; float* Y = qb;
  if (blockIdx.z == 1) { W = wk; bias = bk; Y = kb; }
  else if (blockIdx.z == 2) { W = wv; bias = bv; Y = vb; }
  gemm_body<true, false, false, false>(W, X, bias, nullptr, lng, lnb, statsIn, nullptr, Y);
}

// ---------------------------------------------------------------------------
// 4) attention via MFMA bf16: one wave per (b,h,64-query tile).
//    S^T(m,l) = K(m,d)*Q(d,l)  [K-dim padded 16->32, quads 2/3 zero]
//    online softmax per column l (cross-quad shuffles)
//    O^T(d,l) = V(d,m)*P^T(m,l) with P via LDS round-trip (B-operand layout)
// ---------------------------------------------------------------------------
__global__ __launch_bounds__(64, 4) void attn_kernel(
    const float* __restrict__ qb, const float* __restrict__ kb,
    const float* __restrict__ vb, const float* __restrict__ mask,
    float* __restrict__ ao)
{
  __shared__ short Pl[2][64 * 40];          // row stride 40 shorts = 80B
  int bh = blockIdx.x;
  int b = bh >> 3, h = bh & 7;
  int lane = threadIdx.x;
  int col = lane & 15;                      // C col / A row index
  int quad = lane >> 4;                     // 0..3
  int l0 = blockIdx.y * 64;
  size_t base = ((size_t)b * CC + h * DK) * LL;
  const float* qp = qb + base;
  const float* kp = kb + base;
  const float* vp = vb + base;
  const float* mp = mask + (size_t)b * LL;

  // Q B-frags: B[k=d=quad*8+j][n=l=col]; d>=16 (quads 2,3) zero-padded
  bf16x8 qf[4];
  #pragma unroll
  for (int f = 0; f < 4; f++) {
    bf16x8 v = {};
    if (quad < 2) {
      int l = l0 + f * 16 + col; int lc = l < LL ? l : LL - 1;
      #pragma unroll
      for (int j = 0; j < 8; j++) v[j] = f2bf(qp[(quad * 8 + j) * LL + lc]);
    }
    qf[f] = v;
  }
  f32x4 of[4];
  float mx[4], psum[4];
  #pragma unroll
  for (int f = 0; f < 4; f++) {
    of[f] = (f32x4){0.f, 0.f, 0.f, 0.f};
    mx[f] = -3.0e38f; psum[f] = 0.f;
  }
  const float scale2 = 0.08838834764831845f * 1.4426950408889634f;  // /sqrt(128)*log2e
  const float NBIG = -1.4427e30f;

  int buf = 0;
  for (int m0 = 0; m0 < LL; m0 += 32, buf ^= 1) {
    // K A-frags (two 16-row m-halves): A[m=col][k=d=quad*8+j], d>=16 zero
    bf16x8 kf0 = {}, kf1 = {};
    if (quad < 2) {
      int m_0 = m0 + col;           int mc0 = m_0 < LL ? m_0 : LL - 1;
      int m_1 = m0 + 16 + col;      int mc1 = m_1 < LL ? m_1 : LL - 1;
      #pragma unroll
      for (int j = 0; j < 8; j++) {
        kf0[j] = f2bf(kp[(quad * 8 + j) * LL + mc0]);
        kf1[j] = f2bf(kp[(quad * 8 + j) * LL + mc1]);
      }
    }
    // V A-frag: A[d=col][k=m=quad*8+j]
    bf16x8 vf;
    {
      int ms = m0 + quad * 8; if (ms > LL - 8) ms = LL - 8;
      const float4 v0 = *reinterpret_cast<const float4*>(&vp[col * LL + ms]);
      const float4 v1 = *reinterpret_cast<const float4*>(&vp[col * LL + ms + 4]);
      vf[0] = f2bf(v0.x); vf[1] = f2bf(v0.y); vf[2] = f2bf(v0.z); vf[3] = f2bf(v0.w);
      vf[4] = f2bf(v1.x); vf[5] = f2bf(v1.y); vf[6] = f2bf(v1.z); vf[7] = f2bf(v1.w);
    }
    // mask rows m = m0+quad*4+r and +16 (clamped float4 loads + validity select)
    float mv[8];
    {
      int ma = m0 + quad * 4; int mca = ma > LL - 4 ? LL - 4 : ma;
      int mb = ma + 16;       int mcb = mb > LL - 4 ? LL - 4 : mb;
      const float4 a4 = *reinterpret_cast<const float4*>(&mp[mca]);
      const float4 b4 = *reinterpret_cast<const float4*>(&mp[mcb]);
      float aa[4] = {a4.x, a4.y, a4.z, a4.w};
      float bb4[4] = {b4.x, b4.y, b4.z, b4.w};
      #pragma unroll
      for (int r = 0; r < 4; r++) {
        mv[r]     = (ma + r < LL) ? aa[r]  : 0.f;
        mv[4 + r] = (mb + r < LL) ? bb4[r] : 0.f;
      }
    }
    // QK^T + online softmax + P store, per l-frag
    #pragma unroll
    for (int f = 0; f < 4; f++) {
      f32x4 z = {0.f, 0.f, 0.f, 0.f};
      f32x4 s0 = __builtin_amdgcn_mfma_f32_16x16x32_bf16(kf0, qf[f], z, 0, 0, 0);
      f32x4 s1 = __builtin_amdgcn_mfma_f32_16x16x32_bf16(kf1, qf[f], z, 0, 0, 0);
      float sc[8];
      #pragma unroll
      for (int r = 0; r < 4; r++) {
        sc[r]     = s0[r] * scale2 * mv[r]     + (1.f - mv[r])     * NBIG;
        sc[4 + r] = s1[r] * scale2 * mv[4 + r] + (1.f - mv[4 + r]) * NBIG;
      }
      float lm = sc[0];
      #pragma unroll
      for (int i = 1; i < 8; i++) lm = fmaxf(lm, sc[i]);
      lm = fmaxf(lm, __shfl_xor(lm, 16));
      lm = fmaxf(lm, __shfl_xor(lm, 32));
      float nm = fmaxf(mx[f], lm);
      float alpha = exp2f(mx[f] - nm);
      mx[f] = nm;
      psum[f] *= alpha;
      of[f] *= alpha;
      float p[8];
      float ps = 0.f;
      #pragma unroll
      for (int i = 0; i < 8; i++) { p[i] = exp2f(sc[i] - nm); ps += p[i]; }
      psum[f] += ps;
      short* row = &Pl[buf][(f * 16 + col) * 40];
      short4 h0 = {f2bf(p[0]), f2bf(p[1]), f2bf(p[2]), f2bf(p[3])};
      short4 h1 = {f2bf(p[4]), f2bf(p[5]), f2bf(p[6]), f2bf(p[7])};
      *reinterpret_cast<short4*>(&row[quad * 4])      = h0;
      *reinterpret_cast<short4*>(&row[16 + quad * 4]) = h1;
    }
    // PV: read P in B layout (k=m=quad*8+j, n=l=col), accumulate O^T
    #pragma unroll
    for (int f = 0; f < 4; f++) {
      bf16x8 pf = *reinterpret_cast<const bf16x8*>(&Pl[buf][(f * 16 + col) * 40 + quad * 8]);
      of[f] = __builtin_amdgcn_mfma_f32_16x16x32_bf16(vf, pf, of[f], 0, 0, 0);
    }
  }
  // epilogue: normalize, write O^T rows d=quad*4+r, col l
  #pragma unroll
  for (int f = 0; f < 4; f++) {
    float s = psum[f];
    s += __shfl_xor(s, 16);
    s += __shfl_xor(s, 32);
    float inv = 1.f / s;
    int lf = l0 + f * 16;
    if (lf < LL) {
      #pragma unroll
      for (int r = 0; r < 4; r++)
        ao[base + (size_t)(quad * 4 + r) * LL + lf + col] = of[f][r] * inv;
    }
  }
}

// ---------------------------------------------------------------------------
extern "C" void kernel_launch(void* const* d_in, const int* in_sizes, int n_in,
                              void* d_out, int out_size, void* d_ws, size_t ws_size,
                              hipStream_t stream) {
  const float* x    = (const float*)d_in[0];
  const float* mask = (const float*)d_in[1];
  const float* dw_w = (const float*)d_in[2];
  const float* dw_b = (const float*)d_in[3];
  const float* pw_w = (const float*)d_in[4];
  const float* pw_b = (const float*)d_in[5];
  const float* wq   = (const float*)d_in[6];
  const float* bq   = (const float*)d_in[7];
  const float* wk   = (const float*)d_in[8];
  const float* bk   = (const float*)d_in[9];
  const float* wvp  = (const float*)d_in[10];
  const float* bv   = (const float*)d_in[11];
  const float* wo   = (const float*)d_in[12];
  const float* bo   = (const float*)d_in[13];
  const float* fcw  = (const float*)d_in[14];
  const float* fcb  = (const float*)d_in[15];
  const float* lng  = (const float*)d_in[16];
  const float* lnb  = (const float*)d_in[17];
  float* out = (float*)d_out;
  float* ws  = (float*)d_ws;

  float* stats = ws;                // 6 regions * 128 floats (64 b * {sum,sumsq})
  float* res = ws + 1024;
  float* tmp = res + NBCL;
  float* qb  = tmp + NBCL;
  float* kb  = qb + NBCL;
  float* vb  = kb + NBCL;

  hipMemsetAsync(stats, 0, 768 * sizeof(float), stream);
  addpos_stats_kernel<<<NBCL / 256, 256, 0, stream>>>(x, res, stats);

  for (int i = 0; i < 4; i++) {
    dwln_kernel<<<BN * CC, 256, 0, stream>>>(
        res, stats + i * 128, lng, lnb, dw_w + i * CC * KK, dw_b + i * CC, tmp);
    gemm_kernel<false, true, true, true><<<dim3(7, BN), 512, 0, stream>>>(
        pw_w + i * CC * CC, tmp, pw_b + i * CC, res,
        nullptr, nullptr, nullptr, stats + (i + 1) * 128, res);
  }
  // QKV in one dispatch (LN fused into X load, stats[4])
  qkv_kernel<<<dim3(7, BN, 3), 512, 0, stream>>>(
      wq, wk, wvp, bq, bk, bv, res, lng, lnb, stats + 4 * 128, qb, kb, vb);
  // attention -> tmp (MFMA bf16)
  attn_kernel<<<dim3(512, 7), 64, 0, stream>>>(qb, kb, vb, mask, tmp);
  // WO projection + residual -> res, stats[5]
  gemm_kernel<false, false, true, true><<<dim3(7, BN), 512, 0, stream>>>(
      wo, tmp, bo, res, nullptr, nullptr, nullptr, stats + 5 * 128, res);
  // FC (LN on load) + ReLU + residual -> d_out
  gemm_kernel<true, true, true, false><<<dim3(7, BN), 512, 0, stream>>>(
      fcw, res, fcb, res, lng, lnb, stats + 5 * 128, nullptr, out);
}

// Round 4
// 327.195 us; speedup vs baseline: 2.3154x; 1.6369x over previous
//
#include <hip/hip_runtime.h>
#include <math.h>

constexpr int BN = 64;
constexpr int CC = 128;
constexpr int LL = 400;
constexpr int DK = 16;
constexpr int KK = 7;
constexpr int CL = CC * LL;              // 51200
constexpr int NBCL = BN * CL;            // 3276800
constexpr float EPSV = 1e-5f;
constexpr float INV_N = 1.0f / (float)CL;

typedef __attribute__((ext_vector_type(8))) short bf16x8;
typedef __attribute__((ext_vector_type(4))) float f32x4;

__device__ __forceinline__ short f2bf(float f) {
  unsigned u = __builtin_bit_cast(unsigned, f);
  u = (u + 0x7fffu + ((u >> 16) & 1u)) >> 16;
  return (short)u;
}

// ---------------------------------------------------------------------------
// 0) pos table: pose[c][l] = sin(l*freq(c) + ph(c)); 51200 entries
// ---------------------------------------------------------------------------
__global__ __launch_bounds__(256) void pos_kernel(float* __restrict__ pose)
{
  int idx = blockIdx.x * 256 + threadIdx.x;     // 200 blocks
  int c = idx / LL, l = idx - c * LL;
  float fc = (float)c;
  float freq, ph;
  if ((c & 1) == 0) { freq = powf(10000.f, -fc / (float)CC);        ph = 0.f; }
  else              { freq = -powf(10000.f, (1.f - fc) / (float)CC); ph = 1.5707963267948966f; }
  pose[idx] = sinf((float)l * freq + ph);
}

// ---------------------------------------------------------------------------
// 1) res = x + pose (broadcast over b), accumulate LN stats per b. float4.
// ---------------------------------------------------------------------------
__global__ __launch_bounds__(256) void addpos_stats_kernel(
    const float* __restrict__ x, const float* __restrict__ pose,
    float* __restrict__ res, float* __restrict__ stats)
{
  int idx4 = blockIdx.x * 256 + threadIdx.x;    // 3200 blocks; 50 blocks per b
  int b = idx4 / (CL / 4);
  int cl4 = (idx4 - b * (CL / 4)) * 4;
  const float4 xv = *reinterpret_cast<const float4*>(&x[(size_t)idx4 * 4]);
  const float4 pv = *reinterpret_cast<const float4*>(&pose[cl4]);
  float4 v = make_float4(xv.x + pv.x, xv.y + pv.y, xv.z + pv.z, xv.w + pv.w);
  *reinterpret_cast<float4*>(&res[(size_t)idx4 * 4]) = v;
  float s1 = v.x + v.y + v.z + v.w;
  float s2 = v.x * v.x + v.y * v.y + v.z * v.z + v.w * v.w;
  #pragma unroll
  for (int off = 32; off > 0; off >>= 1) {
    s1 += __shfl_down(s1, off);
    s2 += __shfl_down(s2, off);
  }
  __shared__ float r1[4], r2[4];
  int wv = threadIdx.x >> 6, lane = threadIdx.x & 63;
  if (lane == 0) { r1[wv] = s1; r2[wv] = s2; }
  __syncthreads();
  if (threadIdx.x == 0) {
    atomicAdd(&stats[b * 2 + 0], r1[0] + r1[1] + r1[2] + r1[3]);
    atomicAdd(&stats[b * 2 + 1], r2[0] + r2[1] + r2[2] + r2[3]);
  }
}

// ---------------------------------------------------------------------------
// 2) depthwise conv7 fused with on-the-fly LayerNorm of its input
// ---------------------------------------------------------------------------
__global__ __launch_bounds__(256) void dwln_kernel(
    const float* __restrict__ res, const float* __restrict__ stats,
    const float* __restrict__ lng, const float* __restrict__ lnb,
    const float* __restrict__ dww, const float* __restrict__ dwb,
    float* __restrict__ outp)
{
  __shared__ float sx[LL + 6];
  int bc = blockIdx.x;
  int b = bc >> 7, c = bc & 127;
  float s1 = stats[b * 2 + 0], s2 = stats[b * 2 + 1];
  float mu = s1 * INV_N;
  float rstd = rsqrtf(s2 * INV_N - mu * mu + EPSV);
  const float* rp = res + (size_t)b * CL + c * LL;
  const float* gp = lng + c * LL;
  const float* bp = lnb + c * LL;
  for (int i = threadIdx.x; i < LL + 6; i += 256) {
    int l = i - 3;
    float v = 0.f;
    if (l >= 0 && l < LL) v = (rp[l] - mu) * rstd * gp[l] + bp[l];
    sx[i] = v;
  }
  __syncthreads();
  float w[KK];
  #pragma unroll
  for (int j = 0; j < KK; j++) w[j] = dww[c * KK + j];   // wave-uniform
  float dbv = dwb[c];
  float* op = outp + (size_t)b * CL + c * LL;
  for (int l = threadIdx.x; l < LL; l += 256) {
    float a = dbv;
    #pragma unroll
    for (int j = 0; j < KK; j++) a += w[j] * sx[l + j];
    op[l] = a;
  }
}

// ---------------------------------------------------------------------------
// 3) MFMA GEMM: Y[b] = W(128x128) @ X[b](128x400) + bias.
//    512 threads = 8 waves; block tile 128(o) x 64(l); K = 128 (4 steps of 32).
//    LDS tiles pre-swizzled into exact MFMA fragment order so every inner-loop
//    read is a conflict-free ds_read_b128 at base + lane*16.
//    A-frag (W): A[m=o0+col][k=c0+quad*8+j] ; B-frag (X): B[k][n=l0+col]
//    D[row=quad*4+r][col] -> o = obase+quad*4+r, l = l0+lf*16+col.
// ---------------------------------------------------------------------------
template<bool LNX, bool RELU, bool ADDRES, bool STATS, bool IBF, bool OBF>
__device__ __forceinline__ void gemm_body(
    const float* __restrict__ W, const void* __restrict__ Xv,
    const float* __restrict__ bias, const float* __restrict__ resid,
    const float* __restrict__ lng, const float* __restrict__ lnb,
    const float* __restrict__ statsIn, float* __restrict__ statsOut,
    void* __restrict__ Yv)
{
  __shared__ short WsF[32 * 512];   // tile t = (o>>4)*4 + (c>>5), [lane][8]
  __shared__ short XsF[16 * 512];   // tile t = (lf)*4 + (c>>5),  [lane][8]
  __shared__ float red[16];
  int tid = threadIdx.x;
  int bb = blockIdx.y;
  int j0 = blockIdx.x * 64;
  float mu = 0.f, rstd = 0.f;
  if (LNX) {
    float s1 = statsIn[bb * 2 + 0], s2 = statsIn[bb * 2 + 1];
    mu = s1 * INV_N;
    rstd = rsqrtf(s2 * INV_N - mu * mu + EPSV);
  }
  // ---- stage W (16384 elems as 4096 float4 groups) ----
  for (int idx = tid; idx < 4096; idx += 512) {
    int o = idx >> 5;
    int c4 = (idx & 31) * 4;
    const float4 w4 = *reinterpret_cast<const float4*>(&W[o * CC + c4]);
    int t = (o >> 4) * 4 + (c4 >> 5);
    int lane = ((c4 >> 3) & 3) * 16 + (o & 15);
    int j = c4 & 7;
    short4 h = {f2bf(w4.x), f2bf(w4.y), f2bf(w4.z), f2bf(w4.w)};
    *reinterpret_cast<short4*>(&WsF[t * 512 + lane * 8 + j]) = h;
  }
  // ---- stage X tile (128c x 64l as 2048 groups of 4 along l) ----
  for (int idx = tid; idx < 2048; idx += 512) {
    int c = idx >> 4;
    int l4 = (idx & 15) * 4;
    int col0 = j0 + l4;
    short hv[4] = {0, 0, 0, 0};
    if (col0 < LL) {
      if (IBF) {
        const unsigned short* Xb = (const unsigned short*)Xv + (size_t)bb * CL;
        ushort4 u = *reinterpret_cast<const ushort4*>(&Xb[c * LL + col0]);
        hv[0] = (short)u.x; hv[1] = (short)u.y; hv[2] = (short)u.z; hv[3] = (short)u.w;
      } else {
        const float* Xb = (const float*)Xv + (size_t)bb * CL;
        float4 v = *reinterpret_cast<const float4*>(&Xb[c * LL + col0]);
        if (LNX) {
          const float4 g = *reinterpret_cast<const float4*>(&lng[c * LL + col0]);
          const float4 bt = *reinterpret_cast<const float4*>(&lnb[c * LL + col0]);
          v.x = (v.x - mu) * rstd * g.x + bt.x;
          v.y = (v.y - mu) * rstd * g.y + bt.y;
          v.z = (v.z - mu) * rstd * g.z + bt.z;
          v.w = (v.w - mu) * rstd * g.w + bt.w;
        }
        hv[0] = f2bf(v.x); hv[1] = f2bf(v.y); hv[2] = f2bf(v.z); hv[3] = f2bf(v.w);
      }
    }
    int t = (l4 >> 4) * 4 + (c >> 5);
    int quad = (c >> 3) & 3;
    int j = c & 7;
    int base = t * 512 + quad * 128 + j;     // + col*8
    int colb = l4 & 15;
    #pragma unroll
    for (int e = 0; e < 4; e++) XsF[base + (colb + e) * 8] = hv[e];
  }
  __syncthreads();
  // ---- MFMA main loop: wave w owns o-tile w (16 rows) ----
  int w = tid >> 6, lane = tid & 63;
  int col = lane & 15, quad = lane >> 4;
  f32x4 acc[4];
  #pragma unroll
  for (int lf = 0; lf < 4; lf++) acc[lf] = (f32x4){0.f, 0.f, 0.f, 0.f};
  #pragma unroll
  for (int kt = 0; kt < 4; kt++) {
    bf16x8 af = *reinterpret_cast<const bf16x8*>(&WsF[(w * 4 + kt) * 512 + lane * 8]);
    #pragma unroll
    for (int lf = 0; lf < 4; lf++) {
      bf16x8 bx = *reinterpret_cast<const bf16x8*>(&XsF[(lf * 4 + kt) * 512 + lane * 8]);
      acc[lf] = __builtin_amdgcn_mfma_f32_16x16x32_bf16(af, bx, acc[lf], 0, 0, 0);
    }
  }
  // ---- epilogue ----
  int obase = w * 16;
  float bv[4];
  #pragma unroll
  for (int r = 0; r < 4; r++) bv[r] = bias[obase + quad * 4 + r];
  float lsum = 0.f, lsq = 0.f;
  #pragma unroll
  for (int lf = 0; lf < 4; lf++) {
    if (j0 + lf * 16 < LL) {
      int l = j0 + lf * 16 + col;
      #pragma unroll
      for (int r = 0; r < 4; r++) {
        float v = acc[lf][r] + bv[r];
        if (RELU) v = fmaxf(v, 0.f);
        size_t oidx = (size_t)bb * CL + (size_t)(obase + quad * 4 + r) * LL + l;
        if (ADDRES) v += resid[oidx];
        if (OBF) ((unsigned short*)Yv)[oidx] = (unsigned short)f2bf(v);
        else     ((float*)Yv)[oidx] = v;
        if (STATS) { lsum += v; lsq += v * v; }
      }
    }
  }
  if (STATS) {
    #pragma unroll
    for (int off = 32; off > 0; off >>= 1) {
      lsum += __shfl_down(lsum, off);
      lsq  += __shfl_down(lsq, off);
    }
    if (lane == 0) { red[w * 2] = lsum; red[w * 2 + 1] = lsq; }
    __syncthreads();
    if (tid == 0) {
      float a = 0.f, b2 = 0.f;
      #pragma unroll
      for (int w2 = 0; w2 < 8; w2++) { a += red[w2 * 2]; b2 += red[w2 * 2 + 1]; }
      atomicAdd(&statsOut[bb * 2 + 0], a);
      atomicAdd(&statsOut[bb * 2 + 1], b2);
    }
  }
}

template<bool LNX, bool RELU, bool ADDRES, bool STATS, bool IBF, bool OBF>
__global__ __launch_bounds__(512) void gemmM(
    const float* __restrict__ W, const void* __restrict__ X,
    const float* __restrict__ bias, const float* __restrict__ resid,
    const float* __restrict__ lng, const float* __restrict__ lnb,
    const float* __restrict__ statsIn, float* __restrict__ statsOut,
    void* __restrict__ Y)
{
  gemm_body<LNX, RELU, ADDRES, STATS, IBF, OBF>(W, X, bias, resid, lng, lnb, statsIn, statsOut, Y);
}

// QKV: three GEMMs sharing X, selected by blockIdx.z; bf16 outputs
__global__ __launch_bounds__(512) void qkv_kernel(
    const float* __restrict__ wq, const float* __restrict__ wk, const float* __restrict__ wv,
    const float* __restrict__ bq, const float* __restrict__ bk, const float* __restrict__ bv,
    const float* __restrict__ X,
    const float* __restrict__ lng, const float* __restrict__ lnb,
    const float* __restrict__ statsIn,
    unsigned short* __restrict__ qb, unsigned short* __restrict__ kb,
    unsigned short* __restrict__ vb)
{
  const float* W = wq; const float* bias = bq; unsigned short* Y = qb;
  if (blockIdx.z == 1) { W = wk; bias = bk; Y = kb; }
  else if (blockIdx.z == 2) { W = wv; bias = bv; Y = vb; }
  gemm_body<true, false, false, false, false, true>(
      W, X, bias, nullptr, lng, lnb, statsIn, nullptr, Y);
}

// ---------------------------------------------------------------------------
// 4) attention via MFMA bf16, bf16 Q/K/V inputs, bf16 output.
// ---------------------------------------------------------------------------
__global__ __launch_bounds__(64, 4) void attn_kernel(
    const unsigned short* __restrict__ qb, const unsigned short* __restrict__ kb,
    const unsigned short* __restrict__ vb, const float* __restrict__ mask,
    unsigned short* __restrict__ ao)
{
  __shared__ short Pl[2][64 * 40];          // row stride 40 shorts = 80B
  int bh = blockIdx.x;
  int b = bh >> 3, h = bh & 7;
  int lane = threadIdx.x;
  int col = lane & 15;
  int quad = lane >> 4;
  int l0 = blockIdx.y * 64;
  size_t base = ((size_t)b * CC + h * DK) * LL;
  const unsigned short* qp = qb + base;
  const unsigned short* kp = kb + base;
  const unsigned short* vp = vb + base;
  const float* mp = mask + (size_t)b * LL;

  bf16x8 qf[4];
  #pragma unroll
  for (int f = 0; f < 4; f++) {
    bf16x8 v = {};
    if (quad < 2) {
      int l = l0 + f * 16 + col; int lc = l < LL ? l : LL - 1;
      #pragma unroll
      for (int j = 0; j < 8; j++) v[j] = (short)qp[(quad * 8 + j) * LL + lc];
    }
    qf[f] = v;
  }
  f32x4 of[4];
  float mx[4], psum[4];
  #pragma unroll
  for (int f = 0; f < 4; f++) {
    of[f] = (f32x4){0.f, 0.f, 0.f, 0.f};
    mx[f] = -3.0e38f; psum[f] = 0.f;
  }
  const float scale2 = 0.08838834764831845f * 1.4426950408889634f;  // /sqrt(128)*log2e
  const float NBIG = -1.4427e30f;

  int buf = 0;
  for (int m0 = 0; m0 < LL; m0 += 32, buf ^= 1) {
    bf16x8 kf0 = {}, kf1 = {};
    if (quad < 2) {
      int m_0 = m0 + col;           int mc0 = m_0 < LL ? m_0 : LL - 1;
      int m_1 = m0 + 16 + col;      int mc1 = m_1 < LL ? m_1 : LL - 1;
      #pragma unroll
      for (int j = 0; j < 8; j++) {
        kf0[j] = (short)kp[(quad * 8 + j) * LL + mc0];
        kf1[j] = (short)kp[(quad * 8 + j) * LL + mc1];
      }
    }
    bf16x8 vf;
    {
      int ms = m0 + quad * 8; if (ms > LL - 8) ms = LL - 8;
      vf = *reinterpret_cast<const bf16x8*>(&vp[col * LL + ms]);
    }
    float mv[8];
    {
      int ma = m0 + quad * 4; int mca = ma > LL - 4 ? LL - 4 : ma;
      int mb = ma + 16;       int mcb = mb > LL - 4 ? LL - 4 : mb;
      const float4 a4 = *reinterpret_cast<const float4*>(&mp[mca]);
      const float4 b4 = *reinterpret_cast<const float4*>(&mp[mcb]);
      float aa[4] = {a4.x, a4.y, a4.z, a4.w};
      float bb4[4] = {b4.x, b4.y, b4.z, b4.w};
      #pragma unroll
      for (int r = 0; r < 4; r++) {
        mv[r]     = (ma + r < LL) ? aa[r]  : 0.f;
        mv[4 + r] = (mb + r < LL) ? bb4[r] : 0.f;
      }
    }
    #pragma unroll
    for (int f = 0; f < 4; f++) {
      f32x4 z = {0.f, 0.f, 0.f, 0.f};
      f32x4 s0 = __builtin_amdgcn_mfma_f32_16x16x32_bf16(kf0, qf[f], z, 0, 0, 0);
      f32x4 s1 = __builtin_amdgcn_mfma_f32_16x16x32_bf16(kf1, qf[f], z, 0, 0, 0);
      float sc[8];
      #pragma unroll
      for (int r = 0; r < 4; r++) {
        sc[r]     = s0[r] * scale2 * mv[r]     + (1.f - mv[r])     * NBIG;
        sc[4 + r] = s1[r] * scale2 * mv[4 + r] + (1.f - mv[4 + r]) * NBIG;
      }
      float lm = sc[0];
      #pragma unroll
      for (int i = 1; i < 8; i++) lm = fmaxf(lm, sc[i]);
      lm = fmaxf(lm, __shfl_xor(lm, 16));
      lm = fmaxf(lm, __shfl_xor(lm, 32));
      float nm = fmaxf(mx[f], lm);
      float alpha = exp2f(mx[f] - nm);
      mx[f] = nm;
      psum[f] *= alpha;
      of[f] *= alpha;
      float p[8];
      float ps = 0.f;
      #pragma unroll
      for (int i = 0; i < 8; i++) { p[i] = exp2f(sc[i] - nm); ps += p[i]; }
      psum[f] += ps;
      short* row = &Pl[buf][(f * 16 + col) * 40];
      short4 h0 = {f2bf(p[0]), f2bf(p[1]), f2bf(p[2]), f2bf(p[3])};
      short4 h1 = {f2bf(p[4]), f2bf(p[5]), f2bf(p[6]), f2bf(p[7])};
      *reinterpret_cast<short4*>(&row[quad * 4])      = h0;
      *reinterpret_cast<short4*>(&row[16 + quad * 4]) = h1;
    }
    #pragma unroll
    for (int f = 0; f < 4; f++) {
      bf16x8 pf = *reinterpret_cast<const bf16x8*>(&Pl[buf][(f * 16 + col) * 40 + quad * 8]);
      of[f] = __builtin_amdgcn_mfma_f32_16x16x32_bf16(vf, pf, of[f], 0, 0, 0);
    }
  }
  #pragma unroll
  for (int f = 0; f < 4; f++) {
    float s = psum[f];
    s += __shfl_xor(s, 16);
    s += __shfl_xor(s, 32);
    float inv = 1.f / s;
    int lf = l0 + f * 16;
    if (lf < LL) {
      #pragma unroll
      for (int r = 0; r < 4; r++)
        ao[base + (size_t)(quad * 4 + r) * LL + lf + col] =
            (unsigned short)f2bf(of[f][r] * inv);
    }
  }
}

// ---------------------------------------------------------------------------
extern "C" void kernel_launch(void* const* d_in, const int* in_sizes, int n_in,
                              void* d_out, int out_size, void* d_ws, size_t ws_size,
                              hipStream_t stream) {
  const float* x    = (const float*)d_in[0];
  const float* mask = (const float*)d_in[1];
  const float* dw_w = (const float*)d_in[2];
  const float* dw_b = (const float*)d_in[3];
  const float* pw_w = (const float*)d_in[4];
  const float* pw_b = (const float*)d_in[5];
  const float* wq   = (const float*)d_in[6];
  const float* bq   = (const float*)d_in[7];
  const float* wk   = (const float*)d_in[8];
  const float* bk   = (const float*)d_in[9];
  const float* wvp  = (const float*)d_in[10];
  const float* bv   = (const float*)d_in[11];
  const float* wo   = (const float*)d_in[12];
  const float* bo   = (const float*)d_in[13];
  const float* fcw  = (const float*)d_in[14];
  const float* fcb  = (const float*)d_in[15];
  const float* lng  = (const float*)d_in[16];
  const float* lnb  = (const float*)d_in[17];
  float* out = (float*)d_out;
  float* ws  = (float*)d_ws;

  float* stats = ws;                      // 1024 floats (6 x 128 used)
  float* pose  = ws + 1024;               // 51200
  float* res   = pose + 51200;            // NBCL fp32
  float* tmp   = res + NBCL;              // NBCL fp32
  unsigned short* qb = (unsigned short*)(tmp + NBCL);   // NBCL bf16 each
  unsigned short* kb = qb + NBCL;
  unsigned short* vb = kb + NBCL;
  unsigned short* tb = vb + NBCL;         // attn out bf16

  hipMemsetAsync(stats, 0, 768 * sizeof(float), stream);
  pos_kernel<<<200, 256, 0, stream>>>(pose);
  addpos_stats_kernel<<<3200, 256, 0, stream>>>(x, pose, res, stats);

  for (int i = 0; i < 4; i++) {
    dwln_kernel<<<BN * CC, 256, 0, stream>>>(
        res, stats + i * 128, lng, lnb, dw_w + i * CC * KK, dw_b + i * CC, tmp);
    gemmM<false, true, true, true, false, false><<<dim3(7, BN), 512, 0, stream>>>(
        pw_w + i * CC * CC, tmp, pw_b + i * CC, res,
        nullptr, nullptr, nullptr, stats + (i + 1) * 128, res);
  }
  // QKV in one dispatch (LN fused into X load, stats[4]); bf16 outputs
  qkv_kernel<<<dim3(7, BN, 3), 512, 0, stream>>>(
      wq, wk, wvp, bq, bk, bv, res, lng, lnb, stats + 4 * 128, qb, kb, vb);
  // attention -> tb (bf16)
  attn_kernel<<<dim3(512, 7), 64, 0, stream>>>(qb, kb, vb, mask, tb);
  // WO projection (bf16 X) + residual -> res, stats[5]
  gemmM<false, false, true, true, true, false><<<dim3(7, BN), 512, 0, stream>>>(
      wo, tb, bo, res, nullptr, nullptr, nullptr, stats + 5 * 128, res);
  // FC (LN on load) + ReLU + residual -> d_out
  gemmM<true, true, true, false, false, false><<<dim3(7, BN), 512, 0, stream>>>(
      fcw, res, fcb, res, lng, lnb, stats + 5 * 128, nullptr, out);
}

// Round 6
// 319.653 us; speedup vs baseline: 2.3700x; 1.0236x over previous
//
#include <hip/hip_runtime.h>
#include <math.h>

constexpr int BN = 64;
constexpr int CC = 128;
constexpr int LL = 400;
constexpr int DK = 16;
constexpr int KK = 7;
constexpr int CL = CC * LL;              // 51200
constexpr int NBCL = BN * CL;            // 3276800
constexpr float EPSV = 1e-5f;
constexpr float INV_N = 1.0f / (float)CL;

typedef __attribute__((ext_vector_type(8))) short bf16x8;
typedef __attribute__((ext_vector_type(4))) float f32x4;

__device__ __forceinline__ short f2bf(float f) {        // RNE
  unsigned u = __builtin_bit_cast(unsigned, f);
  u = (u + 0x7fffu + ((u >> 16) & 1u)) >> 16;
  return (short)u;
}

// ---------------------------------------------------------------------------
// 0a) pos table: pose[c][l] = sin(l*freq(c) + ph(c)); 51200 entries
// ---------------------------------------------------------------------------
__global__ __launch_bounds__(256) void pos_kernel(float* __restrict__ pose)
{
  int idx = blockIdx.x * 256 + threadIdx.x;     // 200 blocks
  int c = idx / LL, l = idx - c * LL;
  float fc = (float)c;
  float freq, ph;
  if ((c & 1) == 0) { freq = powf(10000.f, -fc / (float)CC);        ph = 0.f; }
  else              { freq = -powf(10000.f, (1.f - fc) / (float)CC); ph = 1.5707963267948966f; }
  pose[idx] = sinf((float)l * freq + ph);
}

// ---------------------------------------------------------------------------
// 0b) weight prep: 9 matrices 128x128 fp32 -> bf16 in MFMA A-fragment order.
// ---------------------------------------------------------------------------
__global__ __launch_bounds__(256) void wprep_kernel(
    const float* __restrict__ pw_w, const float* __restrict__ wq,
    const float* __restrict__ wk, const float* __restrict__ wv,
    const float* __restrict__ wo, const float* __restrict__ fcw,
    unsigned short* __restrict__ wf)
{
  int idx = blockIdx.x * 256 + threadIdx.x;     // 576 blocks, 9*16384
  int mat = idx >> 14;
  int e = idx & 16383;
  const float* src;
  if (mat < 4)      src = pw_w + mat * 16384;
  else if (mat == 4) src = wq;
  else if (mat == 5) src = wk;
  else if (mat == 6) src = wv;
  else if (mat == 7) src = wo;
  else               src = fcw;
  int o = e >> 7, c = e & 127;
  int t = (o >> 4) * 4 + (c >> 5);
  int quad = (c >> 3) & 3, col = o & 15, j = c & 7;
  wf[mat * 16384 + t * 512 + (quad * 16 + col) * 8 + j] = (unsigned short)f2bf(src[e]);
}

// ---------------------------------------------------------------------------
// 1) res = x + pose (broadcast over b), accumulate LN stats per b. float4.
// ---------------------------------------------------------------------------
__global__ __launch_bounds__(256) void addpos_stats_kernel(
    const float* __restrict__ x, const float* __restrict__ pose,
    float* __restrict__ res, float* __restrict__ stats)
{
  int idx4 = blockIdx.x * 256 + threadIdx.x;    // 3200 blocks; 50 blocks per b
  int b = idx4 / (CL / 4);
  int cl4 = (idx4 - b * (CL / 4)) * 4;
  const float4 xv = *reinterpret_cast<const float4*>(&x[(size_t)idx4 * 4]);
  const float4 pv = *reinterpret_cast<const float4*>(&pose[cl4]);
  float4 v = make_float4(xv.x + pv.x, xv.y + pv.y, xv.z + pv.z, xv.w + pv.w);
  *reinterpret_cast<float4*>(&res[(size_t)idx4 * 4]) = v;
  float s1 = v.x + v.y + v.z + v.w;
  float s2 = v.x * v.x + v.y * v.y + v.z * v.z + v.w * v.w;
  #pragma unroll
  for (int off = 32; off > 0; off >>= 1) {
    s1 += __shfl_down(s1, off);
    s2 += __shfl_down(s2, off);
  }
  __shared__ float r1[4], r2[4];
  int wv = threadIdx.x >> 6, lane = threadIdx.x & 63;
  if (lane == 0) { r1[wv] = s1; r2[wv] = s2; }
  __syncthreads();
  if (threadIdx.x == 0) {
    atomicAdd(&stats[b * 2 + 0], r1[0] + r1[1] + r1[2] + r1[3]);
    atomicAdd(&stats[b * 2 + 1], r2[0] + r2[1] + r2[2] + r2[3]);
  }
}

// ---------------------------------------------------------------------------
// 2) depthwise conv7 fused with on-the-fly LayerNorm; bf16 output
// ---------------------------------------------------------------------------
__global__ __launch_bounds__(256) void dwln_kernel(
    const float* __restrict__ res, const float* __restrict__ stats,
    const float* __restrict__ lng, const float* __restrict__ lnb,
    const float* __restrict__ dww, const float* __restrict__ dwb,
    unsigned short* __restrict__ outp)
{
  __shared__ float sx[LL + 6];
  int bc = blockIdx.x;
  int b = bc >> 7, c = bc & 127;
  float s1 = stats[b * 2 + 0], s2 = stats[b * 2 + 1];
  float mu = s1 * INV_N;
  float rstd = rsqrtf(s2 * INV_N - mu * mu + EPSV);
  const float* rp = res + (size_t)b * CL + c * LL;
  const float* gp = lng + c * LL;
  const float* bp = lnb + c * LL;
  for (int i = threadIdx.x; i < LL + 6; i += 256) {
    int l = i - 3;
    float v = 0.f;
    if (l >= 0 && l < LL) v = (rp[l] - mu) * rstd * gp[l] + bp[l];
    sx[i] = v;
  }
  __syncthreads();
  float w[KK];
  #pragma unroll
  for (int j = 0; j < KK; j++) w[j] = dww[c * KK + j];   // wave-uniform
  float dbv = dwb[c];
  unsigned short* op = outp + (size_t)b * CL + c * LL;
  for (int l = threadIdx.x; l < LL; l += 256) {
    float a = dbv;
    #pragma unroll
    for (int j = 0; j < KK; j++) a += w[j] * sx[l + j];
    op[l] = (unsigned short)f2bf(a);
  }
}

// ---------------------------------------------------------------------------
// 3) MFMA GEMM: Y[b] = W(128x128) @ X[b](128x400) + bias.
//    W arrives pre-converted in fragment order (pure uint4 copy to LDS).
// ---------------------------------------------------------------------------
template<bool LNX, bool RELU, bool ADDRES, bool STATS, bool IBF, bool OBF>
__device__ __forceinline__ void gemm_body(
    const unsigned short* __restrict__ Wf, const void* __restrict__ Xv,
    const float* __restrict__ bias, const float* __restrict__ resid,
    const float* __restrict__ lng, const float* __restrict__ lnb,
    const float* __restrict__ statsIn, float* __restrict__ statsOut,
    void* __restrict__ Yv)
{
  __shared__ short WsF[32 * 512];   // fragment-ordered, linear copy
  __shared__ short XsF[16 * 512];   // tile t = lf*4 + (c>>5), [lane][8]
  __shared__ float red[16];
  int tid = threadIdx.x;
  int bb = blockIdx.y;
  int j0 = blockIdx.x * 64;
  float mu = 0.f, rstd = 0.f;
  if (LNX) {
    float s1 = statsIn[bb * 2 + 0], s2 = statsIn[bb * 2 + 1];
    mu = s1 * INV_N;
    rstd = rsqrtf(s2 * INV_N - mu * mu + EPSV);
  }
  // ---- stage W: 16384 shorts = 2048 uint4, pure copy ----
  {
    const uint4* src = reinterpret_cast<const uint4*>(Wf);
    uint4* dst = reinterpret_cast<uint4*>(WsF);
    for (int idx = tid; idx < 2048; idx += 512) dst[idx] = src[idx];
  }
  // ---- stage X tile (128c x 64l as 2048 groups of 4 along l) ----
  for (int idx = tid; idx < 2048; idx += 512) {
    int c = idx >> 4;
    int l4 = (idx & 15) * 4;
    int col0 = j0 + l4;
    short hv[4] = {0, 0, 0, 0};
    if (col0 < LL) {
      if (IBF) {
        const unsigned short* Xb = (const unsigned short*)Xv + (size_t)bb * CL;
        ushort4 u = *reinterpret_cast<const ushort4*>(&Xb[c * LL + col0]);
        hv[0] = (short)u.x; hv[1] = (short)u.y; hv[2] = (short)u.z; hv[3] = (short)u.w;
      } else {
        const float* Xb = (const float*)Xv + (size_t)bb * CL;
        float4 v = *reinterpret_cast<const float4*>(&Xb[c * LL + col0]);
        if (LNX) {
          const float4 g = *reinterpret_cast<const float4*>(&lng[c * LL + col0]);
          const float4 bt = *reinterpret_cast<const float4*>(&lnb[c * LL + col0]);
          v.x = (v.x - mu) * rstd * g.x + bt.x;
          v.y = (v.y - mu) * rstd * g.y + bt.y;
          v.z = (v.z - mu) * rstd * g.z + bt.z;
          v.w = (v.w - mu) * rstd * g.w + bt.w;
        }
        hv[0] = f2bf(v.x); hv[1] = f2bf(v.y); hv[2] = f2bf(v.z); hv[3] = f2bf(v.w);
      }
    }
    int t = (l4 >> 4) * 4 + (c >> 5);
    int quad = (c >> 3) & 3;
    int j = c & 7;
    int base = t * 512 + quad * 128 + j;     // + col*8
    int colb = l4 & 15;
    #pragma unroll
    for (int e = 0; e < 4; e++) XsF[base + (colb + e) * 8] = hv[e];
  }
  __syncthreads();
  // ---- MFMA main loop: wave w owns o-tile w (16 rows) ----
  int w = tid >> 6, lane = tid & 63;
  int col = lane & 15, quad = lane >> 4;
  f32x4 acc[4];
  #pragma unroll
  for (int lf = 0; lf < 4; lf++) acc[lf] = (f32x4){0.f, 0.f, 0.f, 0.f};
  #pragma unroll
  for (int kt = 0; kt < 4; kt++) {
    bf16x8 af = *reinterpret_cast<const bf16x8*>(&WsF[(w * 4 + kt) * 512 + lane * 8]);
    #pragma unroll
    for (int lf = 0; lf < 4; lf++) {
      bf16x8 bx = *reinterpret_cast<const bf16x8*>(&XsF[(lf * 4 + kt) * 512 + lane * 8]);
      acc[lf] = __builtin_amdgcn_mfma_f32_16x16x32_bf16(af, bx, acc[lf], 0, 0, 0);
    }
  }
  // ---- epilogue ----
  int obase = w * 16;
  float bv[4];
  #pragma unroll
  for (int r = 0; r < 4; r++) bv[r] = bias[obase + quad * 4 + r];
  float lsum = 0.f, lsq = 0.f;
  #pragma unroll
  for (int lf = 0; lf < 4; lf++) {
    if (j0 + lf * 16 < LL) {
      int l = j0 + lf * 16 + col;
      #pragma unroll
      for (int r = 0; r < 4; r++) {
        float v = acc[lf][r] + bv[r];
        if (RELU) v = fmaxf(v, 0.f);
        size_t oidx = (size_t)bb * CL + (size_t)(obase + quad * 4 + r) * LL + l;
        if (ADDRES) v += resid[oidx];
        if (OBF) ((unsigned short*)Yv)[oidx] = (unsigned short)f2bf(v);
        else     ((float*)Yv)[oidx] = v;
        if (STATS) { lsum += v; lsq += v * v; }
      }
    }
  }
  if (STATS) {
    #pragma unroll
    for (int off = 32; off > 0; off >>= 1) {
      lsum += __shfl_down(lsum, off);
      lsq  += __shfl_down(lsq, off);
    }
    if (lane == 0) { red[w * 2] = lsum; red[w * 2 + 1] = lsq; }
    __syncthreads();
    if (tid == 0) {
      float a = 0.f, b2 = 0.f;
      #pragma unroll
      for (int w2 = 0; w2 < 8; w2++) { a += red[w2 * 2]; b2 += red[w2 * 2 + 1]; }
      atomicAdd(&statsOut[bb * 2 + 0], a);
      atomicAdd(&statsOut[bb * 2 + 1], b2);
    }
  }
}

template<bool LNX, bool RELU, bool ADDRES, bool STATS, bool IBF, bool OBF>
__global__ __launch_bounds__(512) void gemmM(
    const unsigned short* __restrict__ Wf, const void* __restrict__ X,
    const float* __restrict__ bias, const float* __restrict__ resid,
    const float* __restrict__ lng, const float* __restrict__ lnb,
    const float* __restrict__ statsIn, float* __restrict__ statsOut,
    void* __restrict__ Y)
{
  gemm_body<LNX, RELU, ADDRES, STATS, IBF, OBF>(Wf, X, bias, resid, lng, lnb, statsIn, statsOut, Y);
}

// QKV: three GEMMs sharing X, selected by blockIdx.z; bf16 outputs
__global__ __launch_bounds__(512) void qkv_kernel(
    const unsigned short* __restrict__ wf,   // mats 4,5,6
    const float* __restrict__ bq, const float* __restrict__ bk, const float* __restrict__ bv,
    const float* __restrict__ X,
    const float* __restrict__ lng, const float* __restrict__ lnb,
    const float* __restrict__ statsIn,
    unsigned short* __restrict__ qb, unsigned short* __restrict__ kb,
    unsigned short* __restrict__ vb)
{
  const unsigned short* W = wf + 4 * 16384; const float* bias = bq; unsigned short* Y = qb;
  if (blockIdx.z == 1) { W = wf + 5 * 16384; bias = bk; Y = kb; }
  else if (blockIdx.z == 2) { W = wf + 6 * 16384; bias = bv; Y = vb; }
  gemm_body<true, false, false, false, false, true>(
      W, X, bias, nullptr, lng, lnb, statsIn, nullptr, Y);
}

// ---------------------------------------------------------------------------
// 4) attention via MFMA bf16 (round-4 proven version): one wave per
//    (b,h,64-query tile), double-buffered P, short4 RNE stores.
// ---------------------------------------------------------------------------
__global__ __launch_bounds__(64, 4) void attn_kernel(
    const unsigned short* __restrict__ qb, const unsigned short* __restrict__ kb,
    const unsigned short* __restrict__ vb, const float* __restrict__ mask,
    unsigned short* __restrict__ ao)
{
  __shared__ short Pl[2][64 * 40];          // row stride 40 shorts = 80B
  int bh = blockIdx.x;
  int b = bh >> 3, h = bh & 7;
  int lane = threadIdx.x;
  int col = lane & 15;
  int quad = lane >> 4;
  int l0 = blockIdx.y * 64;
  size_t base = ((size_t)b * CC + h * DK) * LL;
  const unsigned short* qp = qb + base;
  const unsigned short* kp = kb + base;
  const unsigned short* vp = vb + base;
  const float* mp = mask + (size_t)b * LL;

  bf16x8 qf[4];
  #pragma unroll
  for (int f = 0; f < 4; f++) {
    bf16x8 v = {};
    if (quad < 2) {
      int l = l0 + f * 16 + col; int lc = l < LL ? l : LL - 1;
      #pragma unroll
      for (int j = 0; j < 8; j++) v[j] = (short)qp[(quad * 8 + j) * LL + lc];
    }
    qf[f] = v;
  }
  f32x4 of[4];
  float mx[4], psum[4];
  #pragma unroll
  for (int f = 0; f < 4; f++) {
    of[f] = (f32x4){0.f, 0.f, 0.f, 0.f};
    mx[f] = -3.0e38f; psum[f] = 0.f;
  }
  const float scale2 = 0.08838834764831845f * 1.4426950408889634f;  // /sqrt(128)*log2e
  const float NBIG = -1.4427e30f;

  int buf = 0;
  for (int m0 = 0; m0 < LL; m0 += 32, buf ^= 1) {
    bf16x8 kf0 = {}, kf1 = {};
    if (quad < 2) {
      int m_0 = m0 + col;           int mc0 = m_0 < LL ? m_0 : LL - 1;
      int m_1 = m0 + 16 + col;      int mc1 = m_1 < LL ? m_1 : LL - 1;
      #pragma unroll
      for (int j = 0; j < 8; j++) {
        kf0[j] = (short)kp[(quad * 8 + j) * LL + mc0];
        kf1[j] = (short)kp[(quad * 8 + j) * LL + mc1];
      }
    }
    bf16x8 vf;
    {
      int ms = m0 + quad * 8; if (ms > LL - 8) ms = LL - 8;
      vf = *reinterpret_cast<const bf16x8*>(&vp[col * LL + ms]);
    }
    float mv[8];
    {
      int ma = m0 + quad * 4; int mca = ma > LL - 4 ? LL - 4 : ma;
      int mb = ma + 16;       int mcb = mb > LL - 4 ? LL - 4 : mb;
      const float4 a4 = *reinterpret_cast<const float4*>(&mp[mca]);
      const float4 b4 = *reinterpret_cast<const float4*>(&mp[mcb]);
      float aa[4] = {a4.x, a4.y, a4.z, a4.w};
      float bb4[4] = {b4.x, b4.y, b4.z, b4.w};
      #pragma unroll
      for (int r = 0; r < 4; r++) {
        mv[r]     = (ma + r < LL) ? aa[r]  : 0.f;
        mv[4 + r] = (mb + r < LL) ? bb4[r] : 0.f;
      }
    }
    #pragma unroll
    for (int f = 0; f < 4; f++) {
      f32x4 z = {0.f, 0.f, 0.f, 0.f};
      f32x4 s0 = __builtin_amdgcn_mfma_f32_16x16x32_bf16(kf0, qf[f], z, 0, 0, 0);
      f32x4 s1 = __builtin_amdgcn_mfma_f32_16x16x32_bf16(kf1, qf[f], z, 0, 0, 0);
      float sc[8];
      #pragma unroll
      for (int r = 0; r < 4; r++) {
        sc[r]     = s0[r] * scale2 * mv[r]     + (1.f - mv[r])     * NBIG;
        sc[4 + r] = s1[r] * scale2 * mv[4 + r] + (1.f - mv[4 + r]) * NBIG;
      }
      float lm = sc[0];
      #pragma unroll
      for (int i = 1; i < 8; i++) lm = fmaxf(lm, sc[i]);
      lm = fmaxf(lm, __shfl_xor(lm, 16));
      lm = fmaxf(lm, __shfl_xor(lm, 32));
      float nm = fmaxf(mx[f], lm);
      float alpha = exp2f(mx[f] - nm);
      mx[f] = nm;
      psum[f] *= alpha;
      of[f] *= alpha;
      float p[8];
      float ps = 0.f;
      #pragma unroll
      for (int i = 0; i < 8; i++) { p[i] = exp2f(sc[i] - nm); ps += p[i]; }
      psum[f] += ps;
      short* row = &Pl[buf][(f * 16 + col) * 40];
      short4 h0 = {f2bf(p[0]), f2bf(p[1]), f2bf(p[2]), f2bf(p[3])};
      short4 h1 = {f2bf(p[4]), f2bf(p[5]), f2bf(p[6]), f2bf(p[7])};
      *reinterpret_cast<short4*>(&row[quad * 4])      = h0;
      *reinterpret_cast<short4*>(&row[16 + quad * 4]) = h1;
    }
    #pragma unroll
    for (int f = 0; f < 4; f++) {
      bf16x8 pf = *reinterpret_cast<const bf16x8*>(&Pl[buf][(f * 16 + col) * 40 + quad * 8]);
      of[f] = __builtin_amdgcn_mfma_f32_16x16x32_bf16(vf, pf, of[f], 0, 0, 0);
    }
  }
  #pragma unroll
  for (int f = 0; f < 4; f++) {
    float s = psum[f];
    s += __shfl_xor(s, 16);
    s += __shfl_xor(s, 32);
    float inv = 1.f / s;
    int lf = l0 + f * 16;
    if (lf < LL) {
      #pragma unroll
      for (int r = 0; r < 4; r++)
        ao[base + (size_t)(quad * 4 + r) * LL + lf + col] =
            (unsigned short)f2bf(of[f][r] * inv);
    }
  }
}

// ---------------------------------------------------------------------------
extern "C" void kernel_launch(void* const* d_in, const int* in_sizes, int n_in,
                              void* d_out, int out_size, void* d_ws, size_t ws_size,
                              hipStream_t stream) {
  const float* x    = (const float*)d_in[0];
  const float* mask = (const float*)d_in[1];
  const float* dw_w = (const float*)d_in[2];
  const float* dw_b = (const float*)d_in[3];
  const float* pw_w = (const float*)d_in[4];
  const float* pw_b = (const float*)d_in[5];
  const float* wq   = (const float*)d_in[6];
  const float* bq   = (const float*)d_in[7];
  const float* wk   = (const float*)d_in[8];
  const float* bk   = (const float*)d_in[9];
  const float* wvp  = (const float*)d_in[10];
  const float* bv   = (const float*)d_in[11];
  const float* wo   = (const float*)d_in[12];
  const float* bo   = (const float*)d_in[13];
  const float* fcw  = (const float*)d_in[14];
  const float* fcb  = (const float*)d_in[15];
  const float* lng  = (const float*)d_in[16];
  const float* lnb  = (const float*)d_in[17];
  float* out = (float*)d_out;
  float* ws  = (float*)d_ws;

  float* stats = ws;                                   // 1024 floats
  float* pose  = ws + 1024;                            // 51200 floats
  unsigned short* wf = (unsigned short*)(pose + 51200); // 9*16384 bf16
  float* res = (float*)(wf + 9 * 16384);               // NBCL fp32
  unsigned short* tmpb = (unsigned short*)(res + NBCL); // NBCL bf16 each:
  unsigned short* qb = tmpb + NBCL;
  unsigned short* kb = qb + NBCL;
  unsigned short* vb = kb + NBCL;
  unsigned short* tb = vb + NBCL;

  hipMemsetAsync(stats, 0, 768 * sizeof(float), stream);
  pos_kernel<<<200, 256, 0, stream>>>(pose);
  wprep_kernel<<<576, 256, 0, stream>>>(pw_w, wq, wk, wvp, wo, fcw, wf);
  addpos_stats_kernel<<<3200, 256, 0, stream>>>(x, pose, res, stats);

  for (int i = 0; i < 4; i++) {
    dwln_kernel<<<BN * CC, 256, 0, stream>>>(
        res, stats + i * 128, lng, lnb, dw_w + i * CC * KK, dw_b + i * CC, tmpb);
    gemmM<false, true, true, true, true, false><<<dim3(7, BN), 512, 0, stream>>>(
        wf + i * 16384, tmpb, pw_b + i * CC, res,
        nullptr, nullptr, nullptr, stats + (i + 1) * 128, res);
  }
  // QKV in one dispatch (LN fused into X load, stats[4]); bf16 outputs
  qkv_kernel<<<dim3(7, BN, 3), 512, 0, stream>>>(
      wf, bq, bk, bv, res, lng, lnb, stats + 4 * 128, qb, kb, vb);
  // attention -> tb (bf16)
  attn_kernel<<<dim3(512, 7), 64, 0, stream>>>(qb, kb, vb, mask, tb);
  // WO projection (bf16 X) + residual -> res, stats[5]
  gemmM<false, false, true, true, true, false><<<dim3(7, BN), 512, 0, stream>>>(
      wf + 7 * 16384, tb, bo, res, nullptr, nullptr, nullptr, stats + 5 * 128, res);
  // FC (LN on load) + ReLU + residual -> d_out
  gemmM<true, true, true, false, false, false><<<dim3(7, BN), 512, 0, stream>>>(
      wf + 8 * 16384, res, fcb, res, lng, lnb, stats + 5 * 128, nullptr, out);
}

// Round 7
// 287.829 us; speedup vs baseline: 2.6320x; 1.1106x over previous
//
#include <hip/hip_runtime.h>
#include <math.h>

constexpr int BN = 64;
constexpr int CC = 128;
constexpr int LL = 400;
constexpr int DK = 16;
constexpr int KK = 7;
constexpr int CL = CC * LL;              // 51200
constexpr int NBCL = BN * CL;            // 3276800
constexpr float EPSV = 1e-5f;
constexpr float INV_N = 1.0f / (float)CL;

typedef __attribute__((ext_vector_type(8))) short bf16x8;
typedef __attribute__((ext_vector_type(4))) float f32x4;

__device__ __forceinline__ short f2bf(float f) {        // RNE
  unsigned u = __builtin_bit_cast(unsigned, f);
  u = (u + 0x7fffu + ((u >> 16) & 1u)) >> 16;
  return (short)u;
}
__device__ __forceinline__ unsigned pkbf(float hi, float lo) {  // truncate-pack
  return __builtin_amdgcn_perm(__builtin_bit_cast(unsigned, hi),
                               __builtin_bit_cast(unsigned, lo), 0x07060302u);
}

// ---------------------------------------------------------------------------
// 0) prep: weight frag-conversion + pos table + stats zero + folded conv bias
// ---------------------------------------------------------------------------
__global__ __launch_bounds__(256) void prep_kernel(
    const float* __restrict__ pw_w, const float* __restrict__ wq,
    const float* __restrict__ wk, const float* __restrict__ wv,
    const float* __restrict__ wo, const float* __restrict__ fcw,
    const float* __restrict__ pw_b, const float* __restrict__ dw_b,
    unsigned short* __restrict__ wf, float* __restrict__ pose,
    float* __restrict__ stats, float* __restrict__ beff)
{
  int blk = blockIdx.x;
  if (blk < 576) {                       // 9 x 128x128 fp32 -> bf16 frag order
    int idx = blk * 256 + threadIdx.x;
    int mat = idx >> 14;
    int e = idx & 16383;
    const float* src;
    if (mat < 4)       src = pw_w + mat * 16384;
    else if (mat == 4) src = wq;
    else if (mat == 5) src = wk;
    else if (mat == 6) src = wv;
    else if (mat == 7) src = wo;
    else               src = fcw;
    int o = e >> 7, c = e & 127;
    int t = (o >> 4) * 4 + (c >> 5);
    int quad = (c >> 3) & 3, col = o & 15, j = c & 7;
    wf[mat * 16384 + t * 512 + (quad * 16 + col) * 8 + j] = (unsigned short)f2bf(src[e]);
  } else if (blk < 776) {                // pos table
    int idx = (blk - 576) * 256 + threadIdx.x;
    int c = idx / LL, l = idx - c * LL;
    float fc = (float)c;
    float freq, ph;
    if ((c & 1) == 0) { freq = powf(10000.f, -fc / (float)CC);        ph = 0.f; }
    else              { freq = -powf(10000.f, (1.f - fc) / (float)CC); ph = 1.5707963267948966f; }
    pose[idx] = sinf((float)l * freq + ph);
  } else if (blk == 776) {               // stats zero
    for (int i = threadIdx.x; i < 1024; i += 256) stats[i] = 0.f;
  } else {                               // beff[i][o] = pw_b + PW @ dw_b
    for (int t = threadIdx.x; t < 512; t += 256) {
      int i = t >> 7, o = t & 127;
      float a = pw_b[t];
      const float* wrow = pw_w + (size_t)i * 16384 + o * 128;
      const float* db = dw_b + i * 128;
      for (int c2 = 0; c2 < 128; c2++) a += wrow[c2] * db[c2];
      beff[t] = a;
    }
  }
}

// ---------------------------------------------------------------------------
// 1) res = x + pose (broadcast over b), accumulate LN stats per b. float4.
// ---------------------------------------------------------------------------
__global__ __launch_bounds__(256) void addpos_stats_kernel(
    const float* __restrict__ x, const float* __restrict__ pose,
    float* __restrict__ res, float* __restrict__ stats)
{
  int idx4 = blockIdx.x * 256 + threadIdx.x;    // 3200 blocks; 50 blocks per b
  int b = idx4 / (CL / 4);
  int cl4 = (idx4 - b * (CL / 4)) * 4;
  const float4 xv = *reinterpret_cast<const float4*>(&x[(size_t)idx4 * 4]);
  const float4 pv = *reinterpret_cast<const float4*>(&pose[cl4]);
  float4 v = make_float4(xv.x + pv.x, xv.y + pv.y, xv.z + pv.z, xv.w + pv.w);
  *reinterpret_cast<float4*>(&res[(size_t)idx4 * 4]) = v;
  float s1 = v.x + v.y + v.z + v.w;
  float s2 = v.x * v.x + v.y * v.y + v.z * v.z + v.w * v.w;
  #pragma unroll
  for (int off = 32; off > 0; off >>= 1) {
    s1 += __shfl_down(s1, off);
    s2 += __shfl_down(s2, off);
  }
  __shared__ float r1[4], r2[4];
  int wv = threadIdx.x >> 6, lane = threadIdx.x & 63;
  if (lane == 0) { r1[wv] = s1; r2[wv] = s2; }
  __syncthreads();
  if (threadIdx.x == 0) {
    atomicAdd(&stats[b * 2 + 0], r1[0] + r1[1] + r1[2] + r1[3]);
    atomicAdd(&stats[b * 2 + 1], r2[0] + r2[1] + r2[2] + r2[3]);
  }
}

// ---------------------------------------------------------------------------
// 2) MFMA GEMM, templated:
//    XMODE 0: X fp32 + LN-on-load     (qkv, fc)
//    XMODE 1: X bf16 direct           (wo)
//    XMODE 2: X fp32 + LN + conv7     (pointwise layers; dwb folded in bias)
//    OMODE 0: Y fp32 linear; 1: Y bf16 linear; 2: Y bf16 transposed (b,h,l,d)
// ---------------------------------------------------------------------------
template<int XMODE, int OMODE, bool RELU, bool ADDRES, bool STATS>
__device__ __forceinline__ void gemm_body(
    const unsigned short* __restrict__ Wf, const void* __restrict__ Xv,
    const float* __restrict__ bias, const float* __restrict__ resid,
    const float* __restrict__ lng, const float* __restrict__ lnb,
    const float* __restrict__ dww,
    const float* __restrict__ statsIn, float* __restrict__ statsOut,
    void* __restrict__ Yv)
{
  __shared__ short WsF[32 * 512];   // fragment-ordered, linear copy
  __shared__ short XsF[16 * 512];   // tile t = lf*4 + (c>>5), [lane][8]
  __shared__ float red[16];
  int tid = threadIdx.x;
  int bb = blockIdx.y;
  int j0 = blockIdx.x * 64;
  float mu = 0.f, rstd = 0.f;
  if (XMODE != 1) {
    float s1 = statsIn[bb * 2 + 0], s2 = statsIn[bb * 2 + 1];
    mu = s1 * INV_N;
    rstd = rsqrtf(s2 * INV_N - mu * mu + EPSV);
  }
  // ---- stage W: 16384 shorts = 2048 uint4, pure copy ----
  {
    const uint4* src = reinterpret_cast<const uint4*>(Wf);
    uint4* dst = reinterpret_cast<uint4*>(WsF);
    for (int idx = tid; idx < 2048; idx += 512) dst[idx] = src[idx];
  }
  // ---- stage X tile (128c x 64l as 2048 groups of 4 along l) ----
  for (int idx = tid; idx < 2048; idx += 512) {
    int c = idx >> 4;
    int l4 = (idx & 15) * 4;
    int col0 = j0 + l4;
    short hv[4] = {0, 0, 0, 0};
    if (XMODE == 2) {
      const float* rp = (const float*)Xv + (size_t)bb * CL + c * LL;
      const float* gp = lng + c * LL;
      const float* bp = lnb + c * LL;
      float xn[12];
      #pragma unroll
      for (int g3 = 0; g3 < 3; g3++) {
        int p0 = col0 - 4 + g3 * 4;
        int pc = p0 < 0 ? 0 : (p0 > LL - 4 ? LL - 4 : p0);
        const float4 rv = *reinterpret_cast<const float4*>(&rp[pc]);
        const float4 gv = *reinterpret_cast<const float4*>(&gp[pc]);
        const float4 bv4 = *reinterpret_cast<const float4*>(&bp[pc]);
        float rr[4] = {rv.x, rv.y, rv.z, rv.w};
        float gg[4] = {gv.x, gv.y, gv.z, gv.w};
        float bbv[4] = {bv4.x, bv4.y, bv4.z, bv4.w};
        #pragma unroll
        for (int e = 0; e < 4; e++) {
          int p = p0 + e;
          float v = (rr[e] - mu) * rstd * gg[e] + bbv[e];
          xn[g3 * 4 + e] = (p >= 0 && p < LL) ? v : 0.f;
        }
      }
      float w7[KK];
      #pragma unroll
      for (int j = 0; j < KK; j++) w7[j] = dww[c * KK + j];
      #pragma unroll
      for (int e = 0; e < 4; e++) {
        float a = 0.f;
        #pragma unroll
        for (int j = 0; j < KK; j++) a += w7[j] * xn[e + j + 1];
        hv[e] = f2bf(a);
      }
    } else if (col0 < LL) {
      if (XMODE == 1) {
        const unsigned short* Xb = (const unsigned short*)Xv + (size_t)bb * CL;
        ushort4 u = *reinterpret_cast<const ushort4*>(&Xb[c * LL + col0]);
        hv[0] = (short)u.x; hv[1] = (short)u.y; hv[2] = (short)u.z; hv[3] = (short)u.w;
      } else {
        const float* Xb = (const float*)Xv + (size_t)bb * CL;
        float4 v = *reinterpret_cast<const float4*>(&Xb[c * LL + col0]);
        const float4 g = *reinterpret_cast<const float4*>(&lng[c * LL + col0]);
        const float4 bt = *reinterpret_cast<const float4*>(&lnb[c * LL + col0]);
        v.x = (v.x - mu) * rstd * g.x + bt.x;
        v.y = (v.y - mu) * rstd * g.y + bt.y;
        v.z = (v.z - mu) * rstd * g.z + bt.z;
        v.w = (v.w - mu) * rstd * g.w + bt.w;
        hv[0] = f2bf(v.x); hv[1] = f2bf(v.y); hv[2] = f2bf(v.z); hv[3] = f2bf(v.w);
      }
    }
    int t = (l4 >> 4) * 4 + (c >> 5);
    int quad = (c >> 3) & 3;
    int j = c & 7;
    int base = t * 512 + quad * 128 + j;     // + col*8
    int colb = l4 & 15;
    #pragma unroll
    for (int e = 0; e < 4; e++) XsF[base + (colb + e) * 8] = hv[e];
  }
  __syncthreads();
  // ---- MFMA main loop: wave w owns o-tile w (16 rows) ----
  int w = tid >> 6, lane = tid & 63;
  int col = lane & 15, quad = lane >> 4;
  f32x4 acc[4];
  #pragma unroll
  for (int lf = 0; lf < 4; lf++) acc[lf] = (f32x4){0.f, 0.f, 0.f, 0.f};
  #pragma unroll
  for (int kt = 0; kt < 4; kt++) {
    bf16x8 af = *reinterpret_cast<const bf16x8*>(&WsF[(w * 4 + kt) * 512 + lane * 8]);
    #pragma unroll
    for (int lf = 0; lf < 4; lf++) {
      bf16x8 bx = *reinterpret_cast<const bf16x8*>(&XsF[(lf * 4 + kt) * 512 + lane * 8]);
      acc[lf] = __builtin_amdgcn_mfma_f32_16x16x32_bf16(af, bx, acc[lf], 0, 0, 0);
    }
  }
  // ---- epilogue ----
  int obase = w * 16;
  float bv[4];
  #pragma unroll
  for (int r = 0; r < 4; r++) bv[r] = bias[obase + quad * 4 + r];
  float lsum = 0.f, lsq = 0.f;
  #pragma unroll
  for (int lf = 0; lf < 4; lf++) {
    if (j0 + lf * 16 < LL) {
      int l = j0 + lf * 16 + col;
      if (OMODE == 2) {
        // h = w, d = quad*4+r contiguous -> one coalesced short4 store
        short4 hv4 = {f2bf(acc[lf][0] + bv[0]), f2bf(acc[lf][1] + bv[1]),
                      f2bf(acc[lf][2] + bv[2]), f2bf(acc[lf][3] + bv[3])};
        *reinterpret_cast<short4*>(
            &((unsigned short*)Yv)[(((size_t)bb * 8 + w) * LL + l) * 16 + quad * 4]) = hv4;
      } else {
        #pragma unroll
        for (int r = 0; r < 4; r++) {
          float v = acc[lf][r] + bv[r];
          if (RELU) v = fmaxf(v, 0.f);
          size_t oidx = (size_t)bb * CL + (size_t)(obase + quad * 4 + r) * LL + l;
          if (ADDRES) v += resid[oidx];
          if (OMODE == 1) ((unsigned short*)Yv)[oidx] = (unsigned short)f2bf(v);
          else            ((float*)Yv)[oidx] = v;
          if (STATS) { lsum += v; lsq += v * v; }
        }
      }
    }
  }
  if (STATS) {
    #pragma unroll
    for (int off = 32; off > 0; off >>= 1) {
      lsum += __shfl_down(lsum, off);
      lsq  += __shfl_down(lsq, off);
    }
    if (lane == 0) { red[w * 2] = lsum; red[w * 2 + 1] = lsq; }
    __syncthreads();
    if (tid == 0) {
      float a = 0.f, b2 = 0.f;
      #pragma unroll
      for (int w2 = 0; w2 < 8; w2++) { a += red[w2 * 2]; b2 += red[w2 * 2 + 1]; }
      atomicAdd(&statsOut[bb * 2 + 0], a);
      atomicAdd(&statsOut[bb * 2 + 1], b2);
    }
  }
}

template<int XMODE, int OMODE, bool RELU, bool ADDRES, bool STATS>
__global__ __launch_bounds__(512) void gemmM(
    const unsigned short* __restrict__ Wf, const void* __restrict__ X,
    const float* __restrict__ bias, const float* __restrict__ resid,
    const float* __restrict__ lng, const float* __restrict__ lnb,
    const float* __restrict__ dww,
    const float* __restrict__ statsIn, float* __restrict__ statsOut,
    void* __restrict__ Y)
{
  gemm_body<XMODE, OMODE, RELU, ADDRES, STATS>(
      Wf, X, bias, resid, lng, lnb, dww, statsIn, statsOut, Y);
}

// QKV: Q,K -> transposed (b,h,l,d) bf16; V -> linear (b,c,l) bf16
__global__ __launch_bounds__(512) void qkv_kernel(
    const unsigned short* __restrict__ wf,
    const float* __restrict__ bq, const float* __restrict__ bk, const float* __restrict__ bv,
    const float* __restrict__ X,
    const float* __restrict__ lng, const float* __restrict__ lnb,
    const float* __restrict__ statsIn,
    unsigned short* __restrict__ qt, unsigned short* __restrict__ kt,
    unsigned short* __restrict__ vb)
{
  if (blockIdx.z == 0)
    gemm_body<0, 2, false, false, false>(wf + 4 * 16384, X, bq, nullptr, lng, lnb,
                                         nullptr, statsIn, nullptr, qt);
  else if (blockIdx.z == 1)
    gemm_body<0, 2, false, false, false>(wf + 5 * 16384, X, bk, nullptr, lng, lnb,
                                         nullptr, statsIn, nullptr, kt);
  else
    gemm_body<0, 1, false, false, false>(wf + 6 * 16384, X, bv, nullptr, lng, lnb,
                                         nullptr, statsIn, nullptr, vb);
}

// ---------------------------------------------------------------------------
// 3) attention via MFMA bf16 (round-4 proven structure); Q/K in (b,h,l,d)
//    layout -> single 16B fragment loads; additive mask; perm-packed P.
// ---------------------------------------------------------------------------
__global__ __launch_bounds__(64, 4) void attn_kernel(
    const unsigned short* __restrict__ qt, const unsigned short* __restrict__ kt,
    const unsigned short* __restrict__ vb, const float* __restrict__ mask,
    unsigned short* __restrict__ ao)
{
  __shared__ short Pl[2][64 * 40];          // row stride 40 shorts = 80B (16B-aligned)
  int bh = blockIdx.x;
  int b = bh >> 3, h = bh & 7;
  int lane = threadIdx.x;
  int col = lane & 15;
  int quad = lane >> 4;
  int l0 = blockIdx.y * 64;
  size_t trow = ((size_t)b * 8 + h) * LL;            // row index for qt/kt
  size_t base = ((size_t)b * CC + h * DK) * LL;      // for vb/ao
  const unsigned short* qp = qt + trow * 16;
  const unsigned short* kp = kt + trow * 16;
  const unsigned short* vp = vb + base;
  const float* mp = mask + (size_t)b * LL;

  bf16x8 qf[4];
  #pragma unroll
  for (int f = 0; f < 4; f++) {
    bf16x8 v = {};
    if (quad < 2) {
      int l = l0 + f * 16 + col; int lc = l < LL ? l : LL - 1;
      v = *reinterpret_cast<const bf16x8*>(&qp[lc * 16 + quad * 8]);
    }
    qf[f] = v;
  }
  f32x4 of[4];
  float mx[4], psum[4];
  #pragma unroll
  for (int f = 0; f < 4; f++) {
    of[f] = (f32x4){0.f, 0.f, 0.f, 0.f};
    mx[f] = -3.0e38f; psum[f] = 0.f;
  }
  const float scale2 = 0.08838834764831845f * 1.4426950408889634f;  // /sqrt(128)*log2e
  const float BIGL = 1.4427e30f;

  int buf = 0;
  for (int m0 = 0; m0 < LL; m0 += 32, buf ^= 1) {
    bf16x8 kf0 = {}, kf1 = {};
    if (quad < 2) {
      int mc0 = m0 + col < LL ? m0 + col : LL - 1;
      int mc1 = m0 + 16 + col < LL ? m0 + 16 + col : LL - 1;
      kf0 = *reinterpret_cast<const bf16x8*>(&kp[mc0 * 16 + quad * 8]);
      kf1 = *reinterpret_cast<const bf16x8*>(&kp[mc1 * 16 + quad * 8]);
    }
    bf16x8 vf;
    {
      int ms = m0 + quad * 8; if (ms > LL - 8) ms = LL - 8;
      vf = *reinterpret_cast<const bf16x8*>(&vp[col * LL + ms]);
    }
    // additive mask: 0 where mask==1 and in-range, -BIG otherwise
    float madd[8];
    {
      int ma = m0 + quad * 4; int mca = ma > LL - 4 ? LL - 4 : ma;
      int mb = ma + 16;       int mcb = mb > LL - 4 ? LL - 4 : mb;
      const float4 a4 = *reinterpret_cast<const float4*>(&mp[mca]);
      const float4 b4 = *reinterpret_cast<const float4*>(&mp[mcb]);
      float aa[4] = {a4.x, a4.y, a4.z, a4.w};
      float bb4[4] = {b4.x, b4.y, b4.z, b4.w};
      #pragma unroll
      for (int r = 0; r < 4; r++) {
        float m1 = (ma + r < LL) ? aa[r]  : 0.f;
        float m2 = (mb + r < LL) ? bb4[r] : 0.f;
        madd[r]     = (m1 - 1.f) * BIGL;
        madd[4 + r] = (m2 - 1.f) * BIGL;
      }
    }
    #pragma unroll
    for (int f = 0; f < 4; f++) {
      f32x4 z = {0.f, 0.f, 0.f, 0.f};
      f32x4 s0 = __builtin_amdgcn_mfma_f32_16x16x32_bf16(kf0, qf[f], z, 0, 0, 0);
      f32x4 s1 = __builtin_amdgcn_mfma_f32_16x16x32_bf16(kf1, qf[f], z, 0, 0, 0);
      float sc[8];
      #pragma unroll
      for (int r = 0; r < 4; r++) {
        sc[r]     = s0[r] * scale2 + madd[r];
        sc[4 + r] = s1[r] * scale2 + madd[4 + r];
      }
      float lm = sc[0];
      #pragma unroll
      for (int i = 1; i < 8; i++) lm = fmaxf(lm, sc[i]);
      lm = fmaxf(lm, __shfl_xor(lm, 16));
      lm = fmaxf(lm, __shfl_xor(lm, 32));
      float nm = fmaxf(mx[f], lm);
      float alpha = exp2f(mx[f] - nm);
      mx[f] = nm;
      psum[f] *= alpha;
      of[f] *= alpha;
      float p[8];
      float ps = 0.f;
      #pragma unroll
      for (int i = 0; i < 8; i++) { p[i] = exp2f(sc[i] - nm); ps += p[i]; }
      psum[f] += ps;
      short* row = &Pl[buf][(f * 16 + col) * 40];
      short4 h0 = __builtin_bit_cast(short4, make_uint2(pkbf(p[1], p[0]), pkbf(p[3], p[2])));
      short4 h1 = __builtin_bit_cast(short4, make_uint2(pkbf(p[5], p[4]), pkbf(p[7], p[6])));
      *reinterpret_cast<short4*>(&row[quad * 4])      = h0;
      *reinterpret_cast<short4*>(&row[16 + quad * 4]) = h1;
    }
    #pragma unroll
    for (int f = 0; f < 4; f++) {
      bf16x8 pf = *reinterpret_cast<const bf16x8*>(&Pl[buf][(f * 16 + col) * 40 + quad * 8]);
      of[f] = __builtin_amdgcn_mfma_f32_16x16x32_bf16(vf, pf, of[f], 0, 0, 0);
    }
  }
  #pragma unroll
  for (int f = 0; f < 4; f++) {
    float s = psum[f];
    s += __shfl_xor(s, 16);
    s += __shfl_xor(s, 32);
    float inv = 1.f / s;
    int lf = l0 + f * 16;
    if (lf < LL) {
      #pragma unroll
      for (int r = 0; r < 4; r++)
        ao[base + (size_t)(quad * 4 + r) * LL + lf + col] =
            (unsigned short)f2bf(of[f][r] * inv);
    }
  }
}

// ---------------------------------------------------------------------------
extern "C" void kernel_launch(void* const* d_in, const int* in_sizes, int n_in,
                              void* d_out, int out_size, void* d_ws, size_t ws_size,
                              hipStream_t stream) {
  const float* x    = (const float*)d_in[0];
  const float* mask = (const float*)d_in[1];
  const float* dw_w = (const float*)d_in[2];
  const float* dw_b = (const float*)d_in[3];
  const float* pw_w = (const float*)d_in[4];
  const float* pw_b = (const float*)d_in[5];
  const float* wq   = (const float*)d_in[6];
  const float* bq   = (const float*)d_in[7];
  const float* wk   = (const float*)d_in[8];
  const float* bk   = (const float*)d_in[9];
  const float* wvp  = (const float*)d_in[10];
  const float* bv   = (const float*)d_in[11];
  const float* wo   = (const float*)d_in[12];
  const float* bo   = (const float*)d_in[13];
  const float* fcw  = (const float*)d_in[14];
  const float* fcb  = (const float*)d_in[15];
  const float* lng  = (const float*)d_in[16];
  const float* lnb  = (const float*)d_in[17];
  float* out = (float*)d_out;
  float* ws  = (float*)d_ws;

  float* stats = ws;                                    // 1024 f
  float* pose  = ws + 1024;                             // 51200 f
  float* beff  = pose + 51200;                          // 512 f
  unsigned short* wf = (unsigned short*)(beff + 512);   // 9*16384 bf16
  float* res = (float*)(wf + 9 * 16384);                // NBCL fp32
  unsigned short* qt = (unsigned short*)(res + NBCL);   // NBCL bf16 each:
  unsigned short* kt = qt + NBCL;
  unsigned short* vb = kt + NBCL;
  unsigned short* tb = vb + NBCL;

  prep_kernel<<<778, 256, 0, stream>>>(pw_w, wq, wk, wvp, wo, fcw, pw_b, dw_b,
                                       wf, pose, stats, beff);
  addpos_stats_kernel<<<3200, 256, 0, stream>>>(x, pose, res, stats);

  for (int i = 0; i < 4; i++) {
    // LN + depthwise conv fused into X staging; dwb folded into beff
    gemmM<2, 0, true, true, true><<<dim3(7, BN), 512, 0, stream>>>(
        wf + i * 16384, res, beff + i * CC, res, lng, lnb,
        dw_w + i * CC * KK, stats + i * 128, stats + (i + 1) * 128, res);
  }
  // QKV in one dispatch (LN fused into X load, stats[4])
  qkv_kernel<<<dim3(7, BN, 3), 512, 0, stream>>>(
      wf, bq, bk, bv, res, lng, lnb, stats + 4 * 128, qt, kt, vb);
  // attention -> tb (bf16, (b,c,l) layout)
  attn_kernel<<<dim3(512, 7), 64, 0, stream>>>(qt, kt, vb, mask, tb);
  // WO projection (bf16 X) + residual -> res, stats[5]
  gemmM<1, 0, false, true, true><<<dim3(7, BN), 512, 0, stream>>>(
      wf + 7 * 16384, tb, bo, res, nullptr, nullptr, nullptr,
      nullptr, stats + 5 * 128, res);
  // FC (LN on load) + ReLU + residual -> d_out
  gemmM<0, 0, true, true, false><<<dim3(7, BN), 512, 0, stream>>>(
      wf + 8 * 16384, res, fcb, res, lng, lnb, nullptr,
      stats + 5 * 128, nullptr, out);
}

// Round 8
// 262.468 us; speedup vs baseline: 2.8864x; 1.0966x over previous
//
#include <hip/hip_runtime.h>
#include <math.h>

constexpr int BN = 64;
constexpr int CC = 128;
constexpr int LL = 400;
constexpr int DK = 16;
constexpr int KK = 7;
constexpr int CL = CC * LL;              // 51200
constexpr int NBCL = BN * CL;            // 3276800
constexpr float EPSV = 1e-5f;
constexpr float INV_N = 1.0f / (float)CL;
constexpr float BIGL = 1.4427e30f;

typedef __attribute__((ext_vector_type(8))) short bf16x8;
typedef __attribute__((ext_vector_type(4))) float f32x4;

__device__ __forceinline__ short f2bf(float f) {        // RNE
  unsigned u = __builtin_bit_cast(unsigned, f);
  u = (u + 0x7fffu + ((u >> 16) & 1u)) >> 16;
  return (short)u;
}
__device__ __forceinline__ unsigned pkbf(float hi, float lo) {  // truncate-pack
  return __builtin_amdgcn_perm(__builtin_bit_cast(unsigned, hi),
                               __builtin_bit_cast(unsigned, lo), 0x07060302u);
}

// ---------------------------------------------------------------------------
// 0) prep: weight frag-conversion + pos table + stats zero + folded conv bias
//    + precomputed additive attention mask (log2 domain, padded to 416)
// ---------------------------------------------------------------------------
__global__ __launch_bounds__(256) void prep_kernel(
    const float* __restrict__ pw_w, const float* __restrict__ wq,
    const float* __restrict__ wk, const float* __restrict__ wv,
    const float* __restrict__ wo, const float* __restrict__ fcw,
    const float* __restrict__ pw_b, const float* __restrict__ dw_b,
    const float* __restrict__ mask,
    unsigned short* __restrict__ wf, float* __restrict__ pose,
    float* __restrict__ stats, float* __restrict__ beff,
    float* __restrict__ maddb)
{
  int blk = blockIdx.x;
  if (blk < 576) {                       // 9 x 128x128 fp32 -> bf16 frag order
    int idx = blk * 256 + threadIdx.x;
    int mat = idx >> 14;
    int e = idx & 16383;
    const float* src;
    if (mat < 4)       src = pw_w + mat * 16384;
    else if (mat == 4) src = wq;
    else if (mat == 5) src = wk;
    else if (mat == 6) src = wv;
    else if (mat == 7) src = wo;
    else               src = fcw;
    int o = e >> 7, c = e & 127;
    int t = (o >> 4) * 4 + (c >> 5);
    int quad = (c >> 3) & 3, col = o & 15, j = c & 7;
    wf[mat * 16384 + t * 512 + (quad * 16 + col) * 8 + j] = (unsigned short)f2bf(src[e]);
  } else if (blk < 776) {                // pos table
    int idx = (blk - 576) * 256 + threadIdx.x;
    int c = idx / LL, l = idx - c * LL;
    float fc = (float)c;
    float freq, ph;
    if ((c & 1) == 0) { freq = powf(10000.f, -fc / (float)CC);        ph = 0.f; }
    else              { freq = -powf(10000.f, (1.f - fc) / (float)CC); ph = 1.5707963267948966f; }
    pose[idx] = sinf((float)l * freq + ph);
  } else if (blk == 776) {               // stats zero
    for (int i = threadIdx.x; i < 1024; i += 256) stats[i] = 0.f;
  } else if (blk == 777) {               // beff[i][o] = pw_b + PW @ dw_b
    for (int t = threadIdx.x; t < 512; t += 256) {
      int i = t >> 7, o = t & 127;
      float a = pw_b[t];
      const float* wrow = pw_w + (size_t)i * 16384 + o * 128;
      const float* db = dw_b + i * 128;
      for (int c2 = 0; c2 < 128; c2++) a += wrow[c2] * db[c2];
      beff[t] = a;
    }
  } else {                               // additive mask, 64 x 416
    int idx = (blk - 778) * 256 + threadIdx.x;   // 104 blocks
    int b = idx / 416, m = idx - b * 416;
    maddb[idx] = (m < LL) ? (mask[b * LL + m] - 1.f) * BIGL : -BIGL;
  }
}

// ---------------------------------------------------------------------------
// 1) res = x + pose (broadcast over b), accumulate LN stats per b. float4.
// ---------------------------------------------------------------------------
__global__ __launch_bounds__(256) void addpos_stats_kernel(
    const float* __restrict__ x, const float* __restrict__ pose,
    float* __restrict__ res, float* __restrict__ stats)
{
  int idx4 = blockIdx.x * 256 + threadIdx.x;    // 3200 blocks; 50 blocks per b
  int b = idx4 / (CL / 4);
  int cl4 = (idx4 - b * (CL / 4)) * 4;
  const float4 xv = *reinterpret_cast<const float4*>(&x[(size_t)idx4 * 4]);
  const float4 pv = *reinterpret_cast<const float4*>(&pose[cl4]);
  float4 v = make_float4(xv.x + pv.x, xv.y + pv.y, xv.z + pv.z, xv.w + pv.w);
  *reinterpret_cast<float4*>(&res[(size_t)idx4 * 4]) = v;
  float s1 = v.x + v.y + v.z + v.w;
  float s2 = v.x * v.x + v.y * v.y + v.z * v.z + v.w * v.w;
  #pragma unroll
  for (int off = 32; off > 0; off >>= 1) {
    s1 += __shfl_down(s1, off);
    s2 += __shfl_down(s2, off);
  }
  __shared__ float r1[4], r2[4];
  int wv = threadIdx.x >> 6, lane = threadIdx.x & 63;
  if (lane == 0) { r1[wv] = s1; r2[wv] = s2; }
  __syncthreads();
  if (threadIdx.x == 0) {
    atomicAdd(&stats[b * 2 + 0], r1[0] + r1[1] + r1[2] + r1[3]);
    atomicAdd(&stats[b * 2 + 1], r2[0] + r2[1] + r2[2] + r2[3]);
  }
}

// ---------------------------------------------------------------------------
// 2) MFMA GEMM, templated (W fragments loaded straight from global wf):
//    XMODE 0: X fp32 + LN-on-load     (qkv, fc)
//    XMODE 1: X bf16 direct           (wo)
//    XMODE 2: X fp32 + LN + conv7     (pointwise layers; dwb folded in bias)
//    OMODE 0: Y fp32 linear; 1: Y bf16 linear; 2: Y bf16 transposed (b,h,l,d)
// ---------------------------------------------------------------------------
template<int XMODE, int OMODE, bool RELU, bool ADDRES, bool STATS>
__device__ __forceinline__ void gemm_body(
    const unsigned short* __restrict__ Wf, const void* __restrict__ Xv,
    const float* __restrict__ bias, const float* __restrict__ resid,
    const float* __restrict__ lng, const float* __restrict__ lnb,
    const float* __restrict__ dww,
    const float* __restrict__ statsIn, float* __restrict__ statsOut,
    void* __restrict__ Yv)
{
  __shared__ short XsF[16 * 512];   // tile t = lf*4 + (c>>5), [lane][8]
  __shared__ float red[16];
  int tid = threadIdx.x;
  int bb = blockIdx.y;
  int j0 = blockIdx.x * 64;
  int w = tid >> 6, lane = tid & 63;
  // ---- W fragments direct from global (pre-swizzled; L2-hot) ----
  bf16x8 af[4];
  #pragma unroll
  for (int kt = 0; kt < 4; kt++)
    af[kt] = *reinterpret_cast<const bf16x8*>(&Wf[(w * 4 + kt) * 512 + lane * 8]);
  float mu = 0.f, rstd = 0.f;
  if (XMODE != 1) {
    float s1 = statsIn[bb * 2 + 0], s2 = statsIn[bb * 2 + 1];
    mu = s1 * INV_N;
    rstd = rsqrtf(s2 * INV_N - mu * mu + EPSV);
  }
  // ---- stage X tile (128c x 64l as 2048 groups of 4 along l) ----
  for (int idx = tid; idx < 2048; idx += 512) {
    int c = idx >> 4;
    int l4 = (idx & 15) * 4;
    int col0 = j0 + l4;
    short hv[4] = {0, 0, 0, 0};
    if (XMODE == 2) {
      const float* rp = (const float*)Xv + (size_t)bb * CL + c * LL;
      const float* gp = lng + c * LL;
      const float* bp = lnb + c * LL;
      float xn[12];
      #pragma unroll
      for (int g3 = 0; g3 < 3; g3++) {
        int p0 = col0 - 4 + g3 * 4;
        int pc = p0 < 0 ? 0 : (p0 > LL - 4 ? LL - 4 : p0);
        const float4 rv = *reinterpret_cast<const float4*>(&rp[pc]);
        const float4 gv = *reinterpret_cast<const float4*>(&gp[pc]);
        const float4 bv4 = *reinterpret_cast<const float4*>(&bp[pc]);
        float rr[4] = {rv.x, rv.y, rv.z, rv.w};
        float gg[4] = {gv.x, gv.y, gv.z, gv.w};
        float bbv[4] = {bv4.x, bv4.y, bv4.z, bv4.w};
        #pragma unroll
        for (int e = 0; e < 4; e++) {
          int p = p0 + e;
          float v = (rr[e] - mu) * rstd * gg[e] + bbv[e];
          xn[g3 * 4 + e] = (p >= 0 && p < LL) ? v : 0.f;
        }
      }
      float w7[KK];
      #pragma unroll
      for (int j = 0; j < KK; j++) w7[j] = dww[c * KK + j];
      #pragma unroll
      for (int e = 0; e < 4; e++) {
        float a = 0.f;
        #pragma unroll
        for (int j = 0; j < KK; j++) a += w7[j] * xn[e + j + 1];
        hv[e] = f2bf(a);
      }
    } else if (col0 < LL) {
      if (XMODE == 1) {
        const unsigned short* Xb = (const unsigned short*)Xv + (size_t)bb * CL;
        ushort4 u = *reinterpret_cast<const ushort4*>(&Xb[c * LL + col0]);
        hv[0] = (short)u.x; hv[1] = (short)u.y; hv[2] = (short)u.z; hv[3] = (short)u.w;
      } else {
        const float* Xb = (const float*)Xv + (size_t)bb * CL;
        float4 v = *reinterpret_cast<const float4*>(&Xb[c * LL + col0]);
        const float4 g = *reinterpret_cast<const float4*>(&lng[c * LL + col0]);
        const float4 bt = *reinterpret_cast<const float4*>(&lnb[c * LL + col0]);
        v.x = (v.x - mu) * rstd * g.x + bt.x;
        v.y = (v.y - mu) * rstd * g.y + bt.y;
        v.z = (v.z - mu) * rstd * g.z + bt.z;
        v.w = (v.w - mu) * rstd * g.w + bt.w;
        hv[0] = f2bf(v.x); hv[1] = f2bf(v.y); hv[2] = f2bf(v.z); hv[3] = f2bf(v.w);
      }
    }
    int t = (l4 >> 4) * 4 + (c >> 5);
    int quad = (c >> 3) & 3;
    int j = c & 7;
    int base = t * 512 + quad * 128 + j;     // + col*8
    int colb = l4 & 15;
    #pragma unroll
    for (int e = 0; e < 4; e++) XsF[base + (colb + e) * 8] = hv[e];
  }
  __syncthreads();
  // ---- MFMA main loop: wave w owns o-tile w (16 rows) ----
  int col = lane & 15, quad = lane >> 4;
  f32x4 acc[4];
  #pragma unroll
  for (int lf = 0; lf < 4; lf++) acc[lf] = (f32x4){0.f, 0.f, 0.f, 0.f};
  #pragma unroll
  for (int kt = 0; kt < 4; kt++) {
    #pragma unroll
    for (int lf = 0; lf < 4; lf++) {
      bf16x8 bx = *reinterpret_cast<const bf16x8*>(&XsF[(lf * 4 + kt) * 512 + lane * 8]);
      acc[lf] = __builtin_amdgcn_mfma_f32_16x16x32_bf16(af[kt], bx, acc[lf], 0, 0, 0);
    }
  }
  // ---- epilogue ----
  int obase = w * 16;
  float bv[4];
  #pragma unroll
  for (int r = 0; r < 4; r++) bv[r] = bias[obase + quad * 4 + r];
  float lsum = 0.f, lsq = 0.f;
  #pragma unroll
  for (int lf = 0; lf < 4; lf++) {
    if (j0 + lf * 16 < LL) {
      int l = j0 + lf * 16 + col;
      if (OMODE == 2) {
        short4 hv4 = {f2bf(acc[lf][0] + bv[0]), f2bf(acc[lf][1] + bv[1]),
                      f2bf(acc[lf][2] + bv[2]), f2bf(acc[lf][3] + bv[3])};
        *reinterpret_cast<short4*>(
            &((unsigned short*)Yv)[(((size_t)bb * 8 + w) * LL + l) * 16 + quad * 4]) = hv4;
      } else {
        #pragma unroll
        for (int r = 0; r < 4; r++) {
          float v = acc[lf][r] + bv[r];
          if (RELU) v = fmaxf(v, 0.f);
          size_t oidx = (size_t)bb * CL + (size_t)(obase + quad * 4 + r) * LL + l;
          if (ADDRES) v += resid[oidx];
          if (OMODE == 1) ((unsigned short*)Yv)[oidx] = (unsigned short)f2bf(v);
          else            ((float*)Yv)[oidx] = v;
          if (STATS) { lsum += v; lsq += v * v; }
        }
      }
    }
  }
  if (STATS) {
    #pragma unroll
    for (int off = 32; off > 0; off >>= 1) {
      lsum += __shfl_down(lsum, off);
      lsq  += __shfl_down(lsq, off);
    }
    if (lane == 0) { red[w * 2] = lsum; red[w * 2 + 1] = lsq; }
    __syncthreads();
    if (tid == 0) {
      float a = 0.f, b2 = 0.f;
      #pragma unroll
      for (int w2 = 0; w2 < 8; w2++) { a += red[w2 * 2]; b2 += red[w2 * 2 + 1]; }
      atomicAdd(&statsOut[bb * 2 + 0], a);
      atomicAdd(&statsOut[bb * 2 + 1], b2);
    }
  }
}

template<int XMODE, int OMODE, bool RELU, bool ADDRES, bool STATS>
__global__ __launch_bounds__(512) void gemmM(
    const unsigned short* __restrict__ Wf, const void* __restrict__ X,
    const float* __restrict__ bias, const float* __restrict__ resid,
    const float* __restrict__ lng, const float* __restrict__ lnb,
    const float* __restrict__ dww,
    const float* __restrict__ statsIn, float* __restrict__ statsOut,
    void* __restrict__ Y)
{
  gemm_body<XMODE, OMODE, RELU, ADDRES, STATS>(
      Wf, X, bias, resid, lng, lnb, dww, statsIn, statsOut, Y);
}

// QKV: Q,K -> transposed (b,h,l,d) bf16; V -> linear (b,c,l) bf16
__global__ __launch_bounds__(512) void qkv_kernel(
    const unsigned short* __restrict__ wf,
    const float* __restrict__ bq, const float* __restrict__ bk, const float* __restrict__ bv,
    const float* __restrict__ X,
    const float* __restrict__ lng, const float* __restrict__ lnb,
    const float* __restrict__ statsIn,
    unsigned short* __restrict__ qt, unsigned short* __restrict__ kt,
    unsigned short* __restrict__ vb)
{
  if (blockIdx.z == 0)
    gemm_body<0, 2, false, false, false>(wf + 4 * 16384, X, bq, nullptr, lng, lnb,
                                         nullptr, statsIn, nullptr, qt);
  else if (blockIdx.z == 1)
    gemm_body<0, 2, false, false, false>(wf + 5 * 16384, X, bk, nullptr, lng, lnb,
                                         nullptr, statsIn, nullptr, kt);
  else
    gemm_body<0, 1, false, false, false>(wf + 6 * 16384, X, bv, nullptr, lng, lnb,
                                         nullptr, statsIn, nullptr, vb);
}

// ---------------------------------------------------------------------------
// 3) attention via MFMA bf16, static-max softmax (scores bounded; any fixed
//    shift is exact for softmax). No running max / rescale chain.
// ---------------------------------------------------------------------------
__global__ __launch_bounds__(64, 4) void attn_kernel(
    const unsigned short* __restrict__ qt, const unsigned short* __restrict__ kt,
    const unsigned short* __restrict__ vb, const float* __restrict__ maddb,
    unsigned short* __restrict__ ao)
{
  __shared__ short Pl[2][64 * 40];          // row stride 40 shorts = 80B (16B-aligned)
  int bh = blockIdx.x;
  int b = bh >> 3, h = bh & 7;
  int lane = threadIdx.x;
  int col = lane & 15;
  int quad = lane >> 4;
  int l0 = blockIdx.y * 64;
  size_t trow = ((size_t)b * 8 + h) * LL;            // row index for qt/kt
  size_t base = ((size_t)b * CC + h * DK) * LL;      // for vb/ao
  const unsigned short* qp = qt + trow * 16;
  const unsigned short* kp = kt + trow * 16;
  const unsigned short* vp = vb + base;
  const float* mb = maddb + (size_t)b * 416;

  bf16x8 qf[4];
  #pragma unroll
  for (int f = 0; f < 4; f++) {
    bf16x8 v = {};
    if (quad < 2) {
      int l = l0 + f * 16 + col; int lc = l < LL ? l : LL - 1;
      v = *reinterpret_cast<const bf16x8*>(&qp[lc * 16 + quad * 8]);
    }
    qf[f] = v;
  }
  f32x4 of[4];
  float psum[4];
  #pragma unroll
  for (int f = 0; f < 4; f++) {
    of[f] = (f32x4){0.f, 0.f, 0.f, 0.f};
    psum[f] = 0.f;
  }
  const float scale2 = 0.08838834764831845f * 1.4426950408889634f;  // /sqrt(128)*log2e

  int buf = 0;
  for (int m0 = 0; m0 < LL; m0 += 32, buf ^= 1) {
    bf16x8 kf0 = {}, kf1 = {};
    if (quad < 2) {
      int mc0 = m0 + col < LL ? m0 + col : LL - 1;
      int mc1 = m0 + 16 + col < LL ? m0 + 16 + col : LL - 1;
      kf0 = *reinterpret_cast<const bf16x8*>(&kp[mc0 * 16 + quad * 8]);
      kf1 = *reinterpret_cast<const bf16x8*>(&kp[mc1 * 16 + quad * 8]);
    }
    bf16x8 vf;
    {
      int ms = m0 + quad * 8; if (ms > LL - 8) ms = LL - 8;
      vf = *reinterpret_cast<const bf16x8*>(&vp[col * LL + ms]);
    }
    // precomputed additive mask (log2 domain; padded region = -BIG)
    const float4 a4 = *reinterpret_cast<const float4*>(&mb[m0 + quad * 4]);
    const float4 b4 = *reinterpret_cast<const float4*>(&mb[m0 + 16 + quad * 4]);
    float madd[8] = {a4.x, a4.y, a4.z, a4.w, b4.x, b4.y, b4.z, b4.w};
    #pragma unroll
    for (int f = 0; f < 4; f++) {
      f32x4 z = {0.f, 0.f, 0.f, 0.f};
      f32x4 s0 = __builtin_amdgcn_mfma_f32_16x16x32_bf16(kf0, qf[f], z, 0, 0, 0);
      f32x4 s1 = __builtin_amdgcn_mfma_f32_16x16x32_bf16(kf1, qf[f], z, 0, 0, 0);
      float p[8];
      #pragma unroll
      for (int r = 0; r < 4; r++) {
        p[r]     = exp2f(s0[r] * scale2 + madd[r]);
        p[4 + r] = exp2f(s1[r] * scale2 + madd[4 + r]);
      }
      float ps = 0.f;
      #pragma unroll
      for (int i = 0; i < 8; i++) ps += p[i];
      psum[f] += ps;
      short* row = &Pl[buf][(f * 16 + col) * 40];
      short4 h0 = __builtin_bit_cast(short4, make_uint2(pkbf(p[1], p[0]), pkbf(p[3], p[2])));
      short4 h1 = __builtin_bit_cast(short4, make_uint2(pkbf(p[5], p[4]), pkbf(p[7], p[6])));
      *reinterpret_cast<short4*>(&row[quad * 4])      = h0;
      *reinterpret_cast<short4*>(&row[16 + quad * 4]) = h1;
    }
    #pragma unroll
    for (int f = 0; f < 4; f++) {
      bf16x8 pf = *reinterpret_cast<const bf16x8*>(&Pl[buf][(f * 16 + col) * 40 + quad * 8]);
      of[f] = __builtin_amdgcn_mfma_f32_16x16x32_bf16(vf, pf, of[f], 0, 0, 0);
    }
  }
  #pragma unroll
  for (int f = 0; f < 4; f++) {
    float s = psum[f];
    s += __shfl_xor(s, 16);
    s += __shfl_xor(s, 32);
    float inv = 1.f / s;
    int lf = l0 + f * 16;
    if (lf < LL) {
      #pragma unroll
      for (int r = 0; r < 4; r++)
        ao[base + (size_t)(quad * 4 + r) * LL + lf + col] =
            (unsigned short)f2bf(of[f][r] * inv);
    }
  }
}

// ---------------------------------------------------------------------------
extern "C" void kernel_launch(void* const* d_in, const int* in_sizes, int n_in,
                              void* d_out, int out_size, void* d_ws, size_t ws_size,
                              hipStream_t stream) {
  const float* x    = (const float*)d_in[0];
  const float* mask = (const float*)d_in[1];
  const float* dw_w = (const float*)d_in[2];
  const float* dw_b = (const float*)d_in[3];
  const float* pw_w = (const float*)d_in[4];
  const float* pw_b = (const float*)d_in[5];
  const float* wq   = (const float*)d_in[6];
  const float* bq   = (const float*)d_in[7];
  const float* wk   = (const float*)d_in[8];
  const float* bk   = (const float*)d_in[9];
  const float* wvp  = (const float*)d_in[10];
  const float* bv   = (const float*)d_in[11];
  const float* wo   = (const float*)d_in[12];
  const float* bo   = (const float*)d_in[13];
  const float* fcw  = (const float*)d_in[14];
  const float* fcb  = (const float*)d_in[15];
  const float* lng  = (const float*)d_in[16];
  const float* lnb  = (const float*)d_in[17];
  float* out = (float*)d_out;
  float* ws  = (float*)d_ws;

  float* stats = ws;                                    // 1024 f
  float* pose  = ws + 1024;                             // 51200 f
  float* beff  = pose + 51200;                          // 512 f
  float* maddb = beff + 512;                            // 64*416 f
  unsigned short* wf = (unsigned short*)(maddb + 64 * 416); // 9*16384 bf16
  float* res = (float*)(wf + 9 * 16384);                // NBCL fp32
  unsigned short* qt = (unsigned short*)(res + NBCL);   // NBCL bf16 each:
  unsigned short* kt = qt + NBCL;
  unsigned short* vb = kt + NBCL;
  unsigned short* tb = vb + NBCL;

  prep_kernel<<<882, 256, 0, stream>>>(pw_w, wq, wk, wvp, wo, fcw, pw_b, dw_b,
                                       mask, wf, pose, stats, beff, maddb);
  addpos_stats_kernel<<<3200, 256, 0, stream>>>(x, pose, res, stats);

  for (int i = 0; i < 4; i++) {
    // LN + depthwise conv fused into X staging; dwb folded into beff
    gemmM<2, 0, true, true, true><<<dim3(7, BN), 512, 0, stream>>>(
        wf + i * 16384, res, beff + i * CC, res, lng, lnb,
        dw_w + i * CC * KK, stats + i * 128, stats + (i + 1) * 128, res);
  }
  // QKV in one dispatch (LN fused into X load, stats[4])
  qkv_kernel<<<dim3(7, BN, 3), 512, 0, stream>>>(
      wf, bq, bk, bv, res, lng, lnb, stats + 4 * 128, qt, kt, vb);
  // attention -> tb (bf16, (b,c,l) layout)
  attn_kernel<<<dim3(512, 7), 64, 0, stream>>>(qt, kt, vb, maddb, tb);
  // WO projection (bf16 X) + residual -> res, stats[5]
  gemmM<1, 0, false, true, true><<<dim3(7, BN), 512, 0, stream>>>(
      wf + 7 * 16384, tb, bo, res, nullptr, nullptr, nullptr,
      nullptr, stats + 5 * 128, res);
  // FC (LN on load) + ReLU + residual -> d_out
  gemmM<0, 0, true, true, false><<<dim3(7, BN), 512, 0, stream>>>(
      wf + 8 * 16384, res, fcb, res, lng, lnb, nullptr,
      stats + 5 * 128, nullptr, out);
}